// Round 13
// baseline (36364.325 us; speedup 1.0000x reference)
//
#include <hip/hip_runtime.h>

#define NB 256    // batch
#define NT 512    // T == MAXLEN
#define NI 512    // INPUTS == M
#define NH 512    // HIDDEN
#define NG 1536   // 3*H
#define NBLK 512  // persistent grid

typedef __attribute__((ext_vector_type(8))) short bf16x8;
typedef __attribute__((ext_vector_type(4))) float f32x4;
typedef __attribute__((ext_vector_type(2))) float f32x2;

#define MFMA(a, b, c) __builtin_amdgcn_mfma_f32_16x16x32_bf16((a), (b), (c), 0, 0, 0)

// barrier/flag word offsets inside bar[] (each flag on its own 256B line)
#define BAR_LEAF(g)   ((g) * 64)           // g<16, +32/step each
#define BAR_ROOT      1024                 // +16/step
#define BAR_GEN       1088                 // +1/step
#define FLG_LOGIT(rt) (1152 + (rt) * 64)   // rt<4,  target 8*(t+1)
#define FLG_GH(rt)    (1664 + (rt) * 64)   // rt<4,  target 24*(t+1)
#define FLG_XT        1920                 // target 128*(t+1)
#define FLG_G(rg)     (2176 + (rg) * 64)   // rg<8,  target 32*(t+1)
#define FLG_GP(b)     (2688 + (b) * 64)    // b<256, target (t+1)
#define BAR_WORDS     20480

__device__ __forceinline__ unsigned short f2bf(float f) {
  unsigned int u = __float_as_uint(f);
  u = u + 0x7FFFu + ((u >> 16) & 1u);
  return (unsigned short)(u >> 16);
}
__device__ __forceinline__ float sigm(float x) { return 1.f / (1.f + __expf(-x)); }

// ---- sc1 (agent-coherent, LLC) stores via relaxed atomics ----
__device__ __forceinline__ void stf(float* p, float v) {
  __hip_atomic_store(p, v, __ATOMIC_RELAXED, __HIP_MEMORY_SCOPE_AGENT);
}
__device__ __forceinline__ void stu32(void* p, unsigned v) {
  __hip_atomic_store((unsigned*)p, v, __ATOMIC_RELAXED, __HIP_MEMORY_SCOPE_AGENT);
}
__device__ __forceinline__ void stu64(void* p, unsigned long long v) {
  __hip_atomic_store((unsigned long long*)p, v, __ATOMIC_RELAXED, __HIP_MEMORY_SCOPE_AGENT);
}
// ---- sc1 pipelined LOADS via inline asm (batched; one waitcnt per burst) ----
__device__ __forceinline__ void ldg16(uint4& d, const void* p) {
  asm volatile("global_load_dwordx4 %0, %1, off sc1" : "=v"(d) : "v"(p));
}
__device__ __forceinline__ void ldg8(float2& d, const void* p) {
  asm volatile("global_load_dwordx2 %0, %1, off sc1" : "=v"(d) : "v"(p));
}
__device__ __forceinline__ void ldg4(float& d, const void* p) {
  asm volatile("global_load_dword %0, %1, off sc1" : "=v"(d) : "v"(p));
}
__device__ __forceinline__ void wait_vm0() {
  asm volatile("s_waitcnt vmcnt(0)" ::: "memory");
  __builtin_amdgcn_sched_barrier(0);   // rule #18
}
__device__ __forceinline__ bf16x8 as_frag(uint4 v) {
  union { uint4 u; bf16x8 f; } c; c.u = v; return c.f;
}

// ---- monotonic relaxed flags ----
__device__ __forceinline__ void flag_add(unsigned* f) {
  __hip_atomic_fetch_add(f, 1u, __ATOMIC_RELAXED, __HIP_MEMORY_SCOPE_AGENT);
}
__device__ __forceinline__ void flag_wait(unsigned* f, unsigned target) {
  while (__hip_atomic_load(f, __ATOMIC_RELAXED, __HIP_MEMORY_SCOPE_AGENT) < target)
    __builtin_amdgcn_s_sleep(1);
}

// 8x cvt + 16x fma on one uint4 of 16 fp8 values
#define FP8_FMA16(PX, A_, ACC) do {                                              \
    f32x2 d0 = __builtin_amdgcn_cvt_pk_f32_fp8((int)(PX).x, false);              \
    f32x2 d1 = __builtin_amdgcn_cvt_pk_f32_fp8((int)(PX).x, true);               \
    f32x2 d2 = __builtin_amdgcn_cvt_pk_f32_fp8((int)(PX).y, false);              \
    f32x2 d3 = __builtin_amdgcn_cvt_pk_f32_fp8((int)(PX).y, true);               \
    f32x2 d4 = __builtin_amdgcn_cvt_pk_f32_fp8((int)(PX).z, false);              \
    f32x2 d5 = __builtin_amdgcn_cvt_pk_f32_fp8((int)(PX).z, true);               \
    f32x2 d6 = __builtin_amdgcn_cvt_pk_f32_fp8((int)(PX).w, false);              \
    f32x2 d7 = __builtin_amdgcn_cvt_pk_f32_fp8((int)(PX).w, true);               \
    (ACC)[0]  = fmaf((A_), d0[0], (ACC)[0]);  (ACC)[1]  = fmaf((A_), d0[1], (ACC)[1]);  \
    (ACC)[2]  = fmaf((A_), d1[0], (ACC)[2]);  (ACC)[3]  = fmaf((A_), d1[1], (ACC)[3]);  \
    (ACC)[4]  = fmaf((A_), d2[0], (ACC)[4]);  (ACC)[5]  = fmaf((A_), d2[1], (ACC)[5]);  \
    (ACC)[6]  = fmaf((A_), d3[0], (ACC)[6]);  (ACC)[7]  = fmaf((A_), d3[1], (ACC)[7]);  \
    (ACC)[8]  = fmaf((A_), d4[0], (ACC)[8]);  (ACC)[9]  = fmaf((A_), d4[1], (ACC)[9]);  \
    (ACC)[10] = fmaf((A_), d5[0], (ACC)[10]); (ACC)[11] = fmaf((A_), d5[1], (ACC)[11]); \
    (ACC)[12] = fmaf((A_), d6[0], (ACC)[12]); (ACC)[13] = fmaf((A_), d6[1], (ACC)[13]); \
    (ACC)[14] = fmaf((A_), d7[0], (ACC)[14]); (ACC)[15] = fmaf((A_), d7[1], (ACC)[15]); \
  } while (0)

// ---------------- generic f32 -> bf16 cast ----------------
__global__ __launch_bounds__(256) void cast_f32_bf16(const float* __restrict__ s,
                                                     unsigned short* __restrict__ d, int n) {
  int i = blockIdx.x * 256 + threadIdx.x;
  int stride = gridDim.x * 256;
  for (; i < n; i += stride) d[i] = f2bf(s[i]);
}

// ---------------- Zt = (bf16 X) @ Wc2^T -> fp8 DENSE-PACKED + per-row scale ----------------
__global__ __launch_bounds__(256) void zt_fp8(unsigned short* __restrict__ XZ,
                                              float* __restrict__ Zsc,
                                              const unsigned short* __restrict__ Wc) {
  __shared__ unsigned short As[32][552];
  __shared__ float Zf[32][512];
  const int tid = threadIdx.x;
  const int row0 = blockIdx.x * 32;
  const uint4* src = (const uint4*)(XZ + (size_t)row0 * 512);
#pragma unroll
  for (int it = 0; it < 8; ++it) {
    int e8 = tid + it * 256;
    uint4 v = src[e8];
    *(uint4*)&As[e8 >> 6][(e8 & 63) * 8] = v;
  }
  __syncthreads();
  const int lane = tid & 63, w = tid >> 6;
  const int al = lane & 15, kg = lane >> 4;
  const int rbase = (w & 1) * 16;
  const int cbase = (w >> 1) * 256;
  for (int cc = 0; cc < 16; ++cc) {
    int col0 = cbase + cc * 16;
    f32x4 acc = {0.f, 0.f, 0.f, 0.f};
    const unsigned short* Bp = Wc + (size_t)(col0 + al) * 1024 + 512;
    for (int k = 0; k < 512; k += 32) {
      bf16x8 av = *(const bf16x8*)&As[rbase + al][k + kg * 8];
      bf16x8 bv = *(const bf16x8*)(Bp + k + kg * 8);
      acc = MFMA(av, bv, acc);
    }
#pragma unroll
    for (int r = 0; r < 4; ++r)
      Zf[rbase + kg * 4 + r][col0 + al] = acc[r];
  }
  __syncthreads();
  unsigned char* Z8 = (unsigned char*)XZ + ((size_t)blockIdx.x << 15);
#pragma unroll 2
  for (int r8 = 0; r8 < 8; ++r8) {
    int row = w * 8 + r8;
    const float* vr = &Zf[row][lane * 8];
    float v0 = vr[0], v1 = vr[1], v2 = vr[2], v3 = vr[3];
    float v4 = vr[4], v5 = vr[5], v6 = vr[6], v7 = vr[7];
    float amax = fmaxf(fmaxf(fmaxf(fabsf(v0), fabsf(v1)), fmaxf(fabsf(v2), fabsf(v3))),
                       fmaxf(fmaxf(fabsf(v4), fabsf(v5)), fmaxf(fabsf(v6), fabsf(v7))));
#pragma unroll
    for (int off = 32; off >= 1; off >>= 1) amax = fmaxf(amax, __shfl_xor(amax, off));
    float inv = amax > 0.f ? 448.f / amax : 0.f;
    int w0 = __builtin_amdgcn_cvt_pk_fp8_f32(v0 * inv, v1 * inv, 0, false);
    w0 = __builtin_amdgcn_cvt_pk_fp8_f32(v2 * inv, v3 * inv, w0, true);
    int w1 = __builtin_amdgcn_cvt_pk_fp8_f32(v4 * inv, v5 * inv, 0, false);
    w1 = __builtin_amdgcn_cvt_pk_fp8_f32(v6 * inv, v7 * inv, w1, true);
    uint2 o; o.x = (unsigned)w0; o.y = (unsigned)w1;
    *(uint2*)(Z8 + ((size_t)row << 9) + lane * 8) = o;
    if (lane == 0) Zsc[row0 + row] = amax * (1.f / 448.f);
  }
}

// ---------------- init: Xt[0] = x_0 gather, Hbf = 0, bar = 0 ----------------
__global__ __launch_bounds__(256) void init_kernel(const float* __restrict__ x,
                                                   unsigned short* __restrict__ Xt,
                                                   unsigned short* __restrict__ Hbf,
                                                   unsigned* __restrict__ bar) {
  int idx = blockIdx.x * 256 + threadIdx.x;
  if (idx < BAR_WORDS) bar[idx] = 0u;
  if (idx < NB * NI) {
    int b = idx >> 9, i = idx & 511;
    Xt[idx] = f2bf(x[((size_t)b * 512 + i) * 512]);
    Hbf[idx] = 0;
  }
}

// ---------------- prologue: Lx[0] = x_0@Wa1^T ; Gx[0] = x_0@Wc1^T + b_comb ----------------
__global__ __launch_bounds__(256) void lxgx0_kernel(const unsigned short* __restrict__ Xt0,
                                                    const unsigned short* __restrict__ Wa,
                                                    const unsigned short* __restrict__ Wc,
                                                    const float* __restrict__ b_comb,
                                                    float* __restrict__ Lx,
                                                    float* __restrict__ Gx) {
  const int tid = threadIdx.x, lane = tid & 63, w = tid >> 6;
  const int al = lane & 15, kg = lane >> 4;
  int T = blockIdx.x;                 // 256 tiles: [0,128) Lx, [128,256) Gx
  int m = T >> 7, tt = T & 127;
  int rt = tt >> 4, ct = tt & 15;
  int row0 = rt * 32 + (w & 1) * 16, col0 = ct * 32 + (w >> 1) * 16;
  const unsigned short* A = Xt0 + (size_t)(row0 + al) * NI;
  const unsigned short* B = (m ? Wc : Wa) + (size_t)(col0 + al) * 1024;
  f32x4 acc = {0.f, 0.f, 0.f, 0.f};
  for (int k = 0; k < 512; k += 32)
    acc = MFMA(*(const bf16x8*)(A + k + kg * 8), *(const bf16x8*)(B + k + kg * 8), acc);
  float* dst = m ? Gx : Lx;
  float bias = m ? b_comb[col0 + al] : 0.f;
#pragma unroll
  for (int r = 0; r < 4; ++r) {
    int row = row0 + kg * 4 + r;
    dst[row * NI + col0 + al] = acc[r] + bias;
  }
}

struct KParams {
  const unsigned char* Z8;    // fp8 Zt: group g (32 rows) dense 16KB at byte g<<15
  const float* Zsc;           // per-row scales [256*512]
  const unsigned short* Wa;   // [512][1024]
  const unsigned short* Whh;  // [1536][512]
  const unsigned short* Wc;   // [512][1024]
  const unsigned short* Wih;  // [1536][512]
  const unsigned short* Wout; // [512][512]
  unsigned short* Xt;         // [2][256][512] bf16 (cc) - gather target
  unsigned short* Hbf;        // [256][512] bf16 h (cc)
  unsigned short* Gbf;        // [256][512] bf16 g (cc)
  float* logits;              // [256][512] (cc)
  float* gh;                  // [256][1536] (cc)
  float* Lx;                  // [2][256][512] f32 x_t@Wa1^T (cc)
  float* Gx;                  // [2][256][512] f32 x_t@Wc1^T + b_comb (cc)
  float* Gp;                  // [256][512] f32 partial ctx (cc)
  const float* x;
  const float* b_attn;
  const float* b_hh;
  const float* b_ih;
  const float* b_comb;
  const float* b_out;
  float* out;
  unsigned* bar;
};

// single per-step global barrier: 16 leaves x 32 blocks -> root(16) -> gen
__device__ __forceinline__ void gbar(unsigned* bar, unsigned gen_expect) {
  asm volatile("s_waitcnt vmcnt(0)" ::: "memory");
  __syncthreads();
  if (threadIdx.x == 0) {
    unsigned old = __hip_atomic_fetch_add(&bar[BAR_LEAF(blockIdx.x >> 5)], 1u,
                                          __ATOMIC_RELAXED, __HIP_MEMORY_SCOPE_AGENT);
    if ((old & 31) == 31) {
      unsigned ro = __hip_atomic_fetch_add(&bar[BAR_ROOT], 1u,
                                           __ATOMIC_RELAXED, __HIP_MEMORY_SCOPE_AGENT);
      if ((ro & 15) == 15)
        __hip_atomic_fetch_add(&bar[BAR_GEN], 1u,
                               __ATOMIC_RELAXED, __HIP_MEMORY_SCOPE_AGENT);
    }
    while (__hip_atomic_load(&bar[BAR_GEN], __ATOMIC_RELAXED, __HIP_MEMORY_SCOPE_AGENT) < gen_expect)
      __builtin_amdgcn_s_sleep(2);
    asm volatile("" ::: "memory");
  }
  __syncthreads();
}

__global__ __launch_bounds__(256, 2) void persistent_kernel(KParams P) {
  // 64KB: per-wave 16KB slice holding fp8 group (b*16 + mh*8 + w*2), pinned all steps
  __shared__ __align__(16) unsigned char Zlds[65536];
  __shared__ float aw[512];
  __shared__ float pS[4][32][16];
  __shared__ float red[8];
  const int bid = blockIdx.x, tid = threadIdx.x;
  const int lane = tid & 63, w = tid >> 6;
  const int al = lane & 15, kg = lane >> 4;

  f32x4 hreg = {0.f, 0.f, 0.f, 0.f};   // GRU h carry (blocks 384..511)

  // ---- one-time LDS fill: wave w pins group (b*16 + mh*8 + w*2) ----
  const int b2_ = bid >> 1, mh_ = bid & 1;
  {
    const unsigned char* src = P.Z8 + ((size_t)(b2_ * 16 + mh_ * 8 + w * 2) << 15)
                               + (size_t)lane * 16;
    unsigned char* dst = &Zlds[w * 16384 + lane * 16];
#pragma unroll
    for (int k = 0; k < 16; ++k) {
      uint4 v = *(const uint4*)(src + ((size_t)k << 10));
      *(uint4*)(dst + (k << 10)) = v;
    }
  }

  for (int t = 0; t < NT; ++t) {
    const int p = t & 1, np = p ^ 1;
    // ========== P1: logits[0,32) | gh[32,128) | idle[128,384) | gather[384,512) ==========
    if (bid < 32) {
      // logits = Lx[p] + h @ Wa2^T + b_attn : 64r x 64c block, wave = 16r x 64c, K=512
      int rt = bid >> 3, ct = bid & 7;
      int row0 = rt * 64 + w * 16, col0 = ct * 64;
      const unsigned short* Ah = P.Hbf + (size_t)(row0 + al) * NH;
      uint4 fh[16];
      float lx[4][4];
#pragma unroll
      for (int i = 0; i < 16; ++i) ldg16(fh[i], Ah + i * 32 + kg * 8);
#pragma unroll
      for (int f = 0; f < 4; ++f) {
        const float* lxp = P.Lx + (size_t)p * (NB * NI)
                         + (size_t)(row0 + kg * 4) * NI + col0 + f * 16 + al;
#pragma unroll
        for (int r = 0; r < 4; ++r) ldg4(lx[f][r], lxp + (size_t)r * NI);
      }
      wait_vm0();
      f32x4 a[4] = {{0,0,0,0},{0,0,0,0},{0,0,0,0},{0,0,0,0}};
#pragma unroll
      for (int i = 0; i < 16; ++i) {
        bf16x8 av = as_frag(fh[i]);
#pragma unroll
        for (int f = 0; f < 4; ++f) {
          const unsigned short* B = P.Wa + (size_t)(col0 + f * 16 + al) * 1024 + 512;
          a[f] = MFMA(av, *(const bf16x8*)(B + i * 32 + kg * 8), a[f]);
        }
      }
#pragma unroll
      for (int f = 0; f < 4; ++f)
#pragma unroll
        for (int r = 0; r < 4; ++r) {
          int row = row0 + kg * 4 + r;
          stf(&P.logits[row * NI + col0 + f * 16 + al],
              lx[f][r] + a[f][r] + P.b_attn[col0 + f * 16 + al]);
        }
      __syncthreads();
      if (tid == 0) flag_add(&P.bar[FLG_LOGIT(rt)]);
    } else if (bid < 128) {
      // gh = h @ Whh^T + b_hh : 64r x 64c block, wave = 16r x 64c
      int bb = bid - 32;
      int rt = bb / 24, ct = bb % 24;
      int row0 = rt * 64 + w * 16, col0 = ct * 64;
      const unsigned short* Ah = P.Hbf + (size_t)(row0 + al) * NH;
      uint4 fa[16];
#pragma unroll
      for (int i = 0; i < 16; ++i) ldg16(fa[i], Ah + i * 32 + kg * 8);
      wait_vm0();
      f32x4 a[4] = {{0,0,0,0},{0,0,0,0},{0,0,0,0},{0,0,0,0}};
#pragma unroll
      for (int i = 0; i < 16; ++i) {
        bf16x8 av = as_frag(fa[i]);
#pragma unroll
        for (int f = 0; f < 4; ++f) {
          const unsigned short* B = P.Whh + (size_t)(col0 + f * 16 + al) * 512;
          a[f] = MFMA(av, *(const bf16x8*)(B + i * 32 + kg * 8), a[f]);
        }
      }
#pragma unroll
      for (int f = 0; f < 4; ++f)
#pragma unroll
        for (int r = 0; r < 4; ++r) {
          int row = row0 + kg * 4 + r;
          stf(&P.gh[row * NG + col0 + f * 16 + al],
              a[f][r] + P.b_hh[col0 + f * 16 + al]);
        }
      __syncthreads();
      if (tid == 0) flag_add(&P.bar[FLG_GH(rt)]);
    } else if (bid < 384) {
      // idle in P1
    } else {
      // gather x_{t+1} into Xt[np]; flag for LxGx blocks
      if (t < NT - 1) {
        for (int e2 = (bid - 384) * 256 + tid; e2 < NB * NI / 2; e2 += 128 * 256) {
          int b = e2 >> 8, i = (e2 & 255) * 2;
          const float* xp = P.x + ((size_t)b * 512 + i) * 512 + t + 1;
          unsigned lo = f2bf(xp[0]);
          unsigned hi = f2bf(xp[512]);
          stu32(&P.Xt[(size_t)np * (NB * NI) + b * 512 + i], lo | (hi << 16));
        }
        __syncthreads();
        if (tid == 0) flag_add(&P.bar[FLG_XT]);
      }
    }

    // ========== P2: softmax (+scale fold) + LDS-pinned/streamed fp8 Zt, flag-gated ==========
    {
      const int b = b2_, mh = mh_;
      if (tid == 0) flag_wait(&P.bar[FLG_LOGIT(b >> 6)], 8u * (t + 1));
      __syncthreads();
      float2 lv;
      ldg8(lv, P.logits + (size_t)b * NI + 2 * tid);
      wait_vm0();
      float mx = fmaxf(lv.x, lv.y);
#pragma unroll
      for (int off = 32; off >= 1; off >>= 1) mx = fmaxf(mx, __shfl_xor(mx, off));
      if (lane == 0) red[w] = mx;
      __syncthreads();
      mx = fmaxf(fmaxf(red[0], red[1]), fmaxf(red[2], red[3]));
      float e0 = __expf(lv.x - mx), e1 = __expf(lv.y - mx);
      float sm = e0 + e1;
#pragma unroll
      for (int off = 32; off >= 1; off >>= 1) sm += __shfl_xor(sm, off);
      if (lane == 0) red[4 + w] = sm;
      __syncthreads();
      sm = (red[4] + red[5]) + (red[6] + red[7]);
      float inv = 1.f / sm;
      // fold per-row fp8 scale into aw
      float2 scl = *(const float2*)(P.Zsc + (size_t)b * 512 + 2 * tid);
      aw[2 * tid] = e0 * inv * scl.x;
      aw[2 * tid + 1] = e1 * inv * scl.y;
      __syncthreads();

      // wave w: group w*2 from LDS (pinned), group w*2+1 streamed from global.
      const int half = lane >> 5, hl = lane & 31;
      const unsigned char* Zb1 = P.Z8 + ((size_t)(b * 16 + mh * 8 + w * 2 + 1) << 15)
                                + (size_t)lane * 16;
      const float* awp = aw + mh * 256 + w * 64;
      float acc[16];
#pragma unroll
      for (int i = 0; i < 16; ++i) acc[i] = 0.f;
      // issue streamed group loads first (land under LDS compute)
      uint4 px[16];
#pragma unroll
      for (int k = 0; k < 16; ++k) px[k] = *(const uint4*)(Zb1 + ((size_t)k << 10));
      // gg=0: LDS-pinned group
      const unsigned char* Zl = &Zlds[w * 16384 + lane * 16];
#pragma unroll
      for (int k = 0; k < 16; ++k) {
        uint4 pl = *(const uint4*)(Zl + (k << 10));
        float a_ = awp[2 * k + half];
        FP8_FMA16(pl, a_, acc);
      }
      // gg=1: streamed group
#pragma unroll
      for (int k = 0; k < 16; ++k) {
        float a_ = awp[32 + 2 * k + half];
        FP8_FMA16(px[k], a_, acc);
      }
      // fold lane-halves (same h-cols, different m-rows), then 4-wave LDS combine
#pragma unroll
      for (int i = 0; i < 16; ++i) acc[i] += __shfl_xor(acc[i], 32);
      if (lane < 32) {
#pragma unroll
        for (int i = 0; i < 16; ++i) pS[w][hl][i] = acc[i];
      }
      __syncthreads();
      const int c0 = 2 * tid, c1 = 2 * tid + 1;
      float s0 = (pS[0][c0 >> 4][c0 & 15] + pS[1][c0 >> 4][c0 & 15])
               + (pS[2][c0 >> 4][c0 & 15] + pS[3][c0 >> 4][c0 & 15]);
      float s1 = (pS[0][c1 >> 4][c1 & 15] + pS[1][c1 >> 4][c1 & 15])
               + (pS[2][c1 >> 4][c1 & 15] + pS[3][c1 >> 4][c1 & 15]);
      if (mh == 0) {
        union { float f[2]; unsigned long long q; } q0;
        q0.f[0] = s0; q0.f[1] = s1;
        stu64(&P.Gp[(size_t)b * NH + c0], q0.q);
        __syncthreads();
        if (tid == 0) flag_add(&P.bar[FLG_GP(b)]);
      } else {
        __syncthreads();
        if (tid == 0) flag_wait(&P.bar[FLG_GP(b)], (unsigned)(t + 1));
        __syncthreads();
        float2 gp2, gx2;
        ldg8(gp2, &P.Gp[(size_t)b * NH + c0]);
        ldg8(gx2, P.Gx + (size_t)p * (NB * NH) + (size_t)b * NH + c0);
        wait_vm0();
        float v0 = fmaxf(gx2.x + gp2.x + s0, 0.f);
        float v1 = fmaxf(gx2.y + gp2.y + s1, 0.f);
        stu32(&P.Gbf[(size_t)b * NH + c0], (unsigned)f2bf(v0) | ((unsigned)f2bf(v1) << 16));
        __syncthreads();
        if (tid == 0) flag_add(&P.bar[FLG_G(b >> 5)]);
      }
    }

    // ========== P3 slot: GRU [384,512) | next-step Lx/Gx [320,384) ==========
    if (bid >= 384) {
      int q = bid - 384;
      int rt = q >> 4, ct = q & 15;
      int row0 = rt * 32 + (w & 1) * 16;
      int j0 = ct * 32 + (w >> 1) * 16;
      if (tid == 0) {
        flag_wait(&P.bar[FLG_G(rt)], 32u * (t + 1));
        flag_wait(&P.bar[FLG_GH(rt >> 1)], 24u * (t + 1));
      }
      __syncthreads();
      const unsigned short* Ag = P.Gbf + (size_t)(row0 + al) * NH;
      const unsigned short* Br = P.Wih + (size_t)(j0 + al) * 512;
      const unsigned short* Bz = P.Wih + (size_t)(j0 + 512 + al) * 512;
      const unsigned short* Bn = P.Wih + (size_t)(j0 + 1024 + al) * 512;
      int j = j0 + al;
      uint4 fa[16];
      float ghv[4][3];
#pragma unroll
      for (int i = 0; i < 16; ++i) ldg16(fa[i], Ag + i * 32 + kg * 8);
#pragma unroll
      for (int r = 0; r < 4; ++r) {
        const float* ghrow = P.gh + (size_t)(row0 + kg * 4 + r) * NG + j;
        ldg4(ghv[r][0], ghrow);
        ldg4(ghv[r][1], ghrow + 512);
        ldg4(ghv[r][2], ghrow + 1024);
      }
      wait_vm0();
      f32x4 ar = {0.f, 0.f, 0.f, 0.f}, az = {0.f, 0.f, 0.f, 0.f}, an = {0.f, 0.f, 0.f, 0.f};
#pragma unroll
      for (int i = 0; i < 16; ++i) {
        ar = MFMA(as_frag(fa[i]), *(const bf16x8*)(Br + i * 32 + kg * 8), ar);
        az = MFMA(as_frag(fa[i]), *(const bf16x8*)(Bz + i * 32 + kg * 8), az);
        an = MFMA(as_frag(fa[i]), *(const bf16x8*)(Bn + i * 32 + kg * 8), an);
      }
      float bir = P.b_ih[j], biz = P.b_ih[j + 512], bin_ = P.b_ih[j + 1024];
#pragma unroll
      for (int r = 0; r < 4; ++r) {
        int row = row0 + kg * 4 + r;
        float rg = sigm(ar[r] + bir + ghv[r][0]);
        float zg = sigm(az[r] + biz + ghv[r][1]);
        float ng = tanhf(an[r] + bin_ + rg * ghv[r][2]);
        float hn = (1.f - zg) * ng + zg * hreg[r];
        hreg[r] = hn;
        unsigned hv = f2bf(hn);
        unsigned ov = __shfl_xor((int)hv, 1);
        if ((al & 1) == 0)
          stu32(&P.Hbf[(size_t)row * NH + (j & ~1)], hv | (ov << 16));
      }
    } else if (bid >= 320) {
      // Lx[np]|Gx[np] = x_{t+1} @ [Wa1|Wc1]^T (+ b_comb) : 32r x 128c per block
      if (t < NT - 1) {
        if (tid == 0) flag_wait(&P.bar[FLG_XT], 128u * (t + 1));
        __syncthreads();
        int q = bid - 320;
        int rg = q >> 3, ctl = q & 7;
        int wr = w & 1, wc = w >> 1;
        int row0 = rg * 32 + wr * 16;
        int colb = ctl * 128 + wc * 64;          // in combined [0,1024); never straddles 512
        const unsigned short* A = P.Xt + (size_t)np * (NB * NI) + (size_t)(row0 + al) * NI;
        uint4 fa[16];
#pragma unroll
        for (int i = 0; i < 16; ++i) ldg16(fa[i], A + i * 32 + kg * 8);
        wait_vm0();
        int m = (colb >= 512);
        int cb = colb - (m ? 512 : 0);
        const unsigned short* Wb = m ? P.Wc : P.Wa;
        f32x4 a[4] = {{0,0,0,0},{0,0,0,0},{0,0,0,0},{0,0,0,0}};
#pragma unroll
        for (int i = 0; i < 16; ++i) {
          bf16x8 av = as_frag(fa[i]);
#pragma unroll
          for (int f = 0; f < 4; ++f) {
            const unsigned short* B = Wb + (size_t)(cb + f * 16 + al) * 1024;
            a[f] = MFMA(av, *(const bf16x8*)(B + i * 32 + kg * 8), a[f]);
          }
        }
        float* dst = (m ? P.Gx : P.Lx) + (size_t)np * (NB * NI);
#pragma unroll
        for (int f = 0; f < 4; ++f) {
          float bias = m ? P.b_comb[cb + f * 16 + al] : 0.f;
#pragma unroll
          for (int r = 0; r < 4; ++r) {
            int row = row0 + kg * 4 + r;
            stf(&dst[row * NI + cb + f * 16 + al], a[f][r] + bias);
          }
        }
      }
    }
    gbar(P.bar, (unsigned)(t + 1));
  }

  // ========== epilogue: out = h_T @ Wout^T + b_out ==========
  if (bid < 128) {
    int rt = bid >> 4, ct = bid & 15;
    int row0 = rt * 32 + (w & 1) * 16;
    int col0 = ct * 32 + (w >> 1) * 16;
    const unsigned short* Ah = P.Hbf + (size_t)(row0 + al) * NH;
    const unsigned short* B0 = P.Wout + (size_t)(col0 + al) * 512;
    uint4 fa[16];
#pragma unroll
    for (int i = 0; i < 16; ++i) ldg16(fa[i], Ah + i * 32 + kg * 8);
    wait_vm0();
    f32x4 acc = {0.f, 0.f, 0.f, 0.f};
#pragma unroll
    for (int i = 0; i < 16; ++i) acc = MFMA(as_frag(fa[i]), *(const bf16x8*)(B0 + i * 32 + kg * 8), acc);
#pragma unroll
    for (int r = 0; r < 4; ++r) {
      int row = row0 + kg * 4 + r;
      P.out[row * 512 + col0 + al] = acc[r] + P.b_out[col0 + al];
    }
  }
}

extern "C" void kernel_launch(void* const* d_in, const int* in_sizes, int n_in,
                              void* d_out, int out_size, void* d_ws, size_t ws_size,
                              hipStream_t stream) {
  const float* x      = (const float*)d_in[0];
  const float* W_attn = (const float*)d_in[1];
  const float* b_attn = (const float*)d_in[2];
  const float* W_comb = (const float*)d_in[3];
  const float* b_comb = (const float*)d_in[4];
  const float* W_ih   = (const float*)d_in[5];
  const float* W_hh   = (const float*)d_in[6];
  const float* b_ih   = (const float*)d_in[7];
  const float* b_hh   = (const float*)d_in[8];
  const float* W_out  = (const float*)d_in[9];
  const float* b_out  = (const float*)d_in[10];

  char* wp = (char*)d_ws;
  size_t off = 0;
  unsigned short* XZ   = (unsigned short*)(wp + off); off += (size_t)NB * NI * NH * 2;   // 128MB
  unsigned short* Wa   = (unsigned short*)(wp + off); off += (size_t)NI * 1024 * 2;
  unsigned short* Whh  = (unsigned short*)(wp + off); off += (size_t)NG * 512 * 2;
  unsigned short* Wc   = (unsigned short*)(wp + off); off += (size_t)NH * 1024 * 2;
  unsigned short* Wih  = (unsigned short*)(wp + off); off += (size_t)NG * 512 * 2;
  unsigned short* Wout = (unsigned short*)(wp + off); off += (size_t)512 * 512 * 2;
  unsigned short* Xt   = (unsigned short*)(wp + off); off += (size_t)2 * NB * NI * 2;
  unsigned short* Hbf  = (unsigned short*)(wp + off); off += (size_t)NB * NH * 2;
  unsigned short* Gbf  = (unsigned short*)(wp + off); off += (size_t)NB * NH * 2;
  float* logits        = (float*)(wp + off); off += (size_t)NB * NI * 4;
  float* gh            = (float*)(wp + off); off += (size_t)NB * NG * 4;
  float* Lx            = (float*)(wp + off); off += (size_t)2 * NB * NI * 4;
  float* Gx            = (float*)(wp + off); off += (size_t)2 * NB * NI * 4;
  float* Gp            = (float*)(wp + off); off += (size_t)NB * NH * 4;
  float* Zsc           = (float*)(wp + off); off += (size_t)NB * NI * 4;   // 512KB scales
  unsigned* bar        = (unsigned*)(wp + off); off += (size_t)BAR_WORDS * 4 + 4096;

  cast_f32_bf16<<<8192, 256, 0, stream>>>(x, XZ, NB * NI * NT);
  cast_f32_bf16<<<512, 256, 0, stream>>>(W_attn, Wa, NI * 1024);
  cast_f32_bf16<<<512, 256, 0, stream>>>(W_hh, Whh, NG * 512);
  cast_f32_bf16<<<512, 256, 0, stream>>>(W_comb, Wc, NH * 1024);
  cast_f32_bf16<<<512, 256, 0, stream>>>(W_ih, Wih, NG * 512);
  cast_f32_bf16<<<512, 256, 0, stream>>>(W_out, Wout, 512 * 512);
  zt_fp8<<<4096, 256, 0, stream>>>(XZ, Zsc, Wc);
  init_kernel<<<512, 256, 0, stream>>>(x, Xt, Hbf, bar);
  lxgx0_kernel<<<256, 256, 0, stream>>>(Xt, Wa, Wc, b_comb, Lx, Gx);

  KParams prm;
  prm.Z8 = (const unsigned char*)XZ; prm.Zsc = Zsc;
  prm.Wa = Wa; prm.Whh = Whh; prm.Wc = Wc; prm.Wih = Wih; prm.Wout = Wout;
  prm.Xt = Xt; prm.Hbf = Hbf; prm.Gbf = Gbf;
  prm.logits = logits; prm.gh = gh; prm.Lx = Lx; prm.Gx = Gx; prm.Gp = Gp;
  prm.x = x; prm.b_attn = b_attn; prm.b_hh = b_hh; prm.b_ih = b_ih; prm.b_out = b_out;
  prm.b_comb = b_comb;
  prm.out = (float*)d_out;
  prm.bar = bar;

  void* kargs[] = { &prm };
  hipError_t e = hipLaunchCooperativeKernel((const void*)persistent_kernel,
                                            dim3(NBLK), dim3(256), kargs, 0, stream);
  if (e != hipSuccess) {
    persistent_kernel<<<dim3(NBLK), dim3(256), 0, stream>>>(prm);
  }
}

// Round 14
// 29627.118 us; speedup vs baseline: 1.2274x; 1.2274x over previous
//
#include <hip/hip_runtime.h>

#define NB 256    // batch
#define NT 512    // T == MAXLEN
#define NI 512    // INPUTS == M
#define NH 512    // HIDDEN
#define NG 1536   // 3*H
#define NBLK 512  // persistent grid

typedef __attribute__((ext_vector_type(8))) short bf16x8;
typedef __attribute__((ext_vector_type(4))) float f32x4;
typedef __attribute__((ext_vector_type(2))) float f32x2;

#define MFMA(a, b, c) __builtin_amdgcn_mfma_f32_16x16x32_bf16((a), (b), (c), 0, 0, 0)

// barrier/flag word offsets inside bar[] (each flag on its own 256B line)
#define BAR_LEAF(g)   ((g) * 64)           // g<16, +32/step each
#define BAR_ROOT      1024                 // +16/step
#define BAR_GEN       1088                 // +1/step
#define FLG_LOGIT(rt) (1152 + (rt) * 64)   // rt<8,  target 16*(t+1)
#define FLG_GH(rt)    (1664 + (rt) * 64)   // rt<4,  target 48*(t+1)
#define FLG_XT        1920                 // target 128*(t+1)
#define FLG_G(rg)     (2176 + (rg) * 64)   // rg<8,  target 32*(t+1)
#define FLG_GP(b)     (2688 + (b) * 64)    // b<256, target (t+1)
#define BAR_WORDS     20480

__device__ __forceinline__ unsigned short f2bf(float f) {
  unsigned int u = __float_as_uint(f);
  u = u + 0x7FFFu + ((u >> 16) & 1u);
  return (unsigned short)(u >> 16);
}
__device__ __forceinline__ float sigm(float x) { return 1.f / (1.f + __expf(-x)); }

// ---- sc1 (agent-coherent, LLC) stores via relaxed atomics ----
__device__ __forceinline__ void stf(float* p, float v) {
  __hip_atomic_store(p, v, __ATOMIC_RELAXED, __HIP_MEMORY_SCOPE_AGENT);
}
__device__ __forceinline__ void stu32(void* p, unsigned v) {
  __hip_atomic_store((unsigned*)p, v, __ATOMIC_RELAXED, __HIP_MEMORY_SCOPE_AGENT);
}
__device__ __forceinline__ void stu64(void* p, unsigned long long v) {
  __hip_atomic_store((unsigned long long*)p, v, __ATOMIC_RELAXED, __HIP_MEMORY_SCOPE_AGENT);
}
// ---- pipelined LOADS via inline asm (batched; one waitcnt per burst) ----
__device__ __forceinline__ void ldg16(uint4& d, const void* p) {
  asm volatile("global_load_dwordx4 %0, %1, off sc1" : "=v"(d) : "v"(p));
}
__device__ __forceinline__ void ldg16p(uint4& d, const void* p) {   // plain, L2-cacheable
  asm volatile("global_load_dwordx4 %0, %1, off" : "=v"(d) : "v"(p));
}
__device__ __forceinline__ void ldg8(float2& d, const void* p) {
  asm volatile("global_load_dwordx2 %0, %1, off sc1" : "=v"(d) : "v"(p));
}
__device__ __forceinline__ void ldg4(float& d, const void* p) {
  asm volatile("global_load_dword %0, %1, off sc1" : "=v"(d) : "v"(p));
}
__device__ __forceinline__ void wait_vm0() {
  asm volatile("s_waitcnt vmcnt(0)" ::: "memory");
  __builtin_amdgcn_sched_barrier(0);   // rule #18
}
__device__ __forceinline__ bf16x8 as_frag(uint4 v) {
  union { uint4 u; bf16x8 f; } c; c.u = v; return c.f;
}

// ---- monotonic relaxed flags ----
__device__ __forceinline__ void flag_add(unsigned* f) {
  __hip_atomic_fetch_add(f, 1u, __ATOMIC_RELAXED, __HIP_MEMORY_SCOPE_AGENT);
}
__device__ __forceinline__ void flag_wait(unsigned* f, unsigned target) {
  while (__hip_atomic_load(f, __ATOMIC_RELAXED, __HIP_MEMORY_SCOPE_AGENT) < target)
    __builtin_amdgcn_s_sleep(1);
}

// 8x cvt + 16x fma on one uint4 of 16 fp8 values
#define FP8_FMA16(PX, A_, ACC) do {                                              \
    f32x2 d0 = __builtin_amdgcn_cvt_pk_f32_fp8((int)(PX).x, false);              \
    f32x2 d1 = __builtin_amdgcn_cvt_pk_f32_fp8((int)(PX).x, true);               \
    f32x2 d2 = __builtin_amdgcn_cvt_pk_f32_fp8((int)(PX).y, false);              \
    f32x2 d3 = __builtin_amdgcn_cvt_pk_f32_fp8((int)(PX).y, true);               \
    f32x2 d4 = __builtin_amdgcn_cvt_pk_f32_fp8((int)(PX).z, false);              \
    f32x2 d5 = __builtin_amdgcn_cvt_pk_f32_fp8((int)(PX).z, true);               \
    f32x2 d6 = __builtin_amdgcn_cvt_pk_f32_fp8((int)(PX).w, false);              \
    f32x2 d7 = __builtin_amdgcn_cvt_pk_f32_fp8((int)(PX).w, true);               \
    (ACC)[0]  = fmaf((A_), d0[0], (ACC)[0]);  (ACC)[1]  = fmaf((A_), d0[1], (ACC)[1]);  \
    (ACC)[2]  = fmaf((A_), d1[0], (ACC)[2]);  (ACC)[3]  = fmaf((A_), d1[1], (ACC)[3]);  \
    (ACC)[4]  = fmaf((A_), d2[0], (ACC)[4]);  (ACC)[5]  = fmaf((A_), d2[1], (ACC)[5]);  \
    (ACC)[6]  = fmaf((A_), d3[0], (ACC)[6]);  (ACC)[7]  = fmaf((A_), d3[1], (ACC)[7]);  \
    (ACC)[8]  = fmaf((A_), d4[0], (ACC)[8]);  (ACC)[9]  = fmaf((A_), d4[1], (ACC)[9]);  \
    (ACC)[10] = fmaf((A_), d5[0], (ACC)[10]); (ACC)[11] = fmaf((A_), d5[1], (ACC)[11]); \
    (ACC)[12] = fmaf((A_), d6[0], (ACC)[12]); (ACC)[13] = fmaf((A_), d6[1], (ACC)[13]); \
    (ACC)[14] = fmaf((A_), d7[0], (ACC)[14]); (ACC)[15] = fmaf((A_), d7[1], (ACC)[15]); \
  } while (0)

// ---------------- generic f32 -> bf16 cast ----------------
__global__ __launch_bounds__(256) void cast_f32_bf16(const float* __restrict__ s,
                                                     unsigned short* __restrict__ d, int n) {
  int i = blockIdx.x * 256 + threadIdx.x;
  int stride = gridDim.x * 256;
  for (; i < n; i += stride) d[i] = f2bf(s[i]);
}

// ---------------- Zt = (bf16 X) @ Wc2^T -> fp8 DENSE-PACKED + per-row scale ----------------
__global__ __launch_bounds__(256) void zt_fp8(unsigned short* __restrict__ XZ,
                                              float* __restrict__ Zsc,
                                              const unsigned short* __restrict__ Wc) {
  __shared__ unsigned short As[32][552];
  __shared__ float Zf[32][512];
  const int tid = threadIdx.x;
  const int row0 = blockIdx.x * 32;
  const uint4* src = (const uint4*)(XZ + (size_t)row0 * 512);
#pragma unroll
  for (int it = 0; it < 8; ++it) {
    int e8 = tid + it * 256;
    uint4 v = src[e8];
    *(uint4*)&As[e8 >> 6][(e8 & 63) * 8] = v;
  }
  __syncthreads();
  const int lane = tid & 63, w = tid >> 6;
  const int al = lane & 15, kg = lane >> 4;
  const int rbase = (w & 1) * 16;
  const int cbase = (w >> 1) * 256;
  for (int cc = 0; cc < 16; ++cc) {
    int col0 = cbase + cc * 16;
    f32x4 acc = {0.f, 0.f, 0.f, 0.f};
    const unsigned short* Bp = Wc + (size_t)(col0 + al) * 1024 + 512;
    for (int k = 0; k < 512; k += 32) {
      bf16x8 av = *(const bf16x8*)&As[rbase + al][k + kg * 8];
      bf16x8 bv = *(const bf16x8*)(Bp + k + kg * 8);
      acc = MFMA(av, bv, acc);
    }
#pragma unroll
    for (int r = 0; r < 4; ++r)
      Zf[rbase + kg * 4 + r][col0 + al] = acc[r];
  }
  __syncthreads();
  unsigned char* Z8 = (unsigned char*)XZ + ((size_t)blockIdx.x << 15);
#pragma unroll 2
  for (int r8 = 0; r8 < 8; ++r8) {
    int row = w * 8 + r8;
    const float* vr = &Zf[row][lane * 8];
    float v0 = vr[0], v1 = vr[1], v2 = vr[2], v3 = vr[3];
    float v4 = vr[4], v5 = vr[5], v6 = vr[6], v7 = vr[7];
    float amax = fmaxf(fmaxf(fmaxf(fabsf(v0), fabsf(v1)), fmaxf(fabsf(v2), fabsf(v3))),
                       fmaxf(fmaxf(fabsf(v4), fabsf(v5)), fmaxf(fabsf(v6), fabsf(v7))));
#pragma unroll
    for (int off = 32; off >= 1; off >>= 1) amax = fmaxf(amax, __shfl_xor(amax, off));
    float inv = amax > 0.f ? 448.f / amax : 0.f;
    int w0 = __builtin_amdgcn_cvt_pk_fp8_f32(v0 * inv, v1 * inv, 0, false);
    w0 = __builtin_amdgcn_cvt_pk_fp8_f32(v2 * inv, v3 * inv, w0, true);
    int w1 = __builtin_amdgcn_cvt_pk_fp8_f32(v4 * inv, v5 * inv, 0, false);
    w1 = __builtin_amdgcn_cvt_pk_fp8_f32(v6 * inv, v7 * inv, w1, true);
    uint2 o; o.x = (unsigned)w0; o.y = (unsigned)w1;
    *(uint2*)(Z8 + ((size_t)row << 9) + lane * 8) = o;
    if (lane == 0) Zsc[row0 + row] = amax * (1.f / 448.f);
  }
}

// ---------------- init: Xt[0] = x_0 gather, Hbf = 0, bar = 0 ----------------
__global__ __launch_bounds__(256) void init_kernel(const float* __restrict__ x,
                                                   unsigned short* __restrict__ Xt,
                                                   unsigned short* __restrict__ Hbf,
                                                   unsigned* __restrict__ bar) {
  int idx = blockIdx.x * 256 + threadIdx.x;
  if (idx < BAR_WORDS) bar[idx] = 0u;
  if (idx < NB * NI) {
    int b = idx >> 9, i = idx & 511;
    Xt[idx] = f2bf(x[((size_t)b * 512 + i) * 512]);
    Hbf[idx] = 0;
  }
}

// ---------------- prologue: Lx[0] = x_0@Wa1^T ; Gx[0] = x_0@Wc1^T + b_comb ----------------
__global__ __launch_bounds__(256) void lxgx0_kernel(const unsigned short* __restrict__ Xt0,
                                                    const unsigned short* __restrict__ Wa,
                                                    const unsigned short* __restrict__ Wc,
                                                    const float* __restrict__ b_comb,
                                                    float* __restrict__ Lx,
                                                    float* __restrict__ Gx) {
  const int tid = threadIdx.x, lane = tid & 63, w = tid >> 6;
  const int al = lane & 15, kg = lane >> 4;
  int T = blockIdx.x;                 // 256 tiles: [0,128) Lx, [128,256) Gx
  int m = T >> 7, tt = T & 127;
  int rt = tt >> 4, ct = tt & 15;
  int row0 = rt * 32 + (w & 1) * 16, col0 = ct * 32 + (w >> 1) * 16;
  const unsigned short* A = Xt0 + (size_t)(row0 + al) * NI;
  const unsigned short* B = (m ? Wc : Wa) + (size_t)(col0 + al) * 1024;
  f32x4 acc = {0.f, 0.f, 0.f, 0.f};
  for (int k = 0; k < 512; k += 32)
    acc = MFMA(*(const bf16x8*)(A + k + kg * 8), *(const bf16x8*)(B + k + kg * 8), acc);
  float* dst = m ? Gx : Lx;
  float bias = m ? b_comb[col0 + al] : 0.f;
#pragma unroll
  for (int r = 0; r < 4; ++r) {
    int row = row0 + kg * 4 + r;
    dst[row * NI + col0 + al] = acc[r] + bias;
  }
}

struct KParams {
  const unsigned char* Z8;    // fp8 Zt: group g (32 rows) dense 16KB at byte g<<15
  const float* Zsc;           // per-row scales [256*512]
  const unsigned short* Wa;   // [512][1024]
  const unsigned short* Whh;  // [1536][512]
  const unsigned short* Wc;   // [512][1024]
  const unsigned short* Wih;  // [1536][512]
  const unsigned short* Wout; // [512][512]
  unsigned short* Xt;         // [2][256][512] bf16 (cc) - gather target
  unsigned short* Hbf;        // [256][512] bf16 h (cc)
  unsigned short* Gbf;        // [256][512] bf16 g (cc)
  float* logits;              // [256][512] (cc)
  float* gh;                  // [256][1536] (cc)
  float* Lx;                  // [2][256][512] f32 x_t@Wa1^T (cc)
  float* Gx;                  // [2][256][512] f32 x_t@Wc1^T + b_comb (cc)
  float* Gp;                  // [256][512] f32 partial ctx (cc)
  const float* x;
  const float* b_attn;
  const float* b_hh;
  const float* b_ih;
  const float* b_comb;
  const float* b_out;
  float* out;
  unsigned* bar;
};

// single per-step global barrier: 16 leaves x 32 blocks -> root(16) -> gen
__device__ __forceinline__ void gbar(unsigned* bar, unsigned gen_expect) {
  asm volatile("s_waitcnt vmcnt(0)" ::: "memory");
  __syncthreads();
  if (threadIdx.x == 0) {
    unsigned old = __hip_atomic_fetch_add(&bar[BAR_LEAF(blockIdx.x >> 5)], 1u,
                                          __ATOMIC_RELAXED, __HIP_MEMORY_SCOPE_AGENT);
    if ((old & 31) == 31) {
      unsigned ro = __hip_atomic_fetch_add(&bar[BAR_ROOT], 1u,
                                           __ATOMIC_RELAXED, __HIP_MEMORY_SCOPE_AGENT);
      if ((ro & 15) == 15)
        __hip_atomic_fetch_add(&bar[BAR_GEN], 1u,
                               __ATOMIC_RELAXED, __HIP_MEMORY_SCOPE_AGENT);
    }
    while (__hip_atomic_load(&bar[BAR_GEN], __ATOMIC_RELAXED, __HIP_MEMORY_SCOPE_AGENT) < gen_expect)
      __builtin_amdgcn_s_sleep(2);
    asm volatile("" ::: "memory");
  }
  __syncthreads();
}

__global__ __launch_bounds__(256, 2) void persistent_kernel(KParams P) {
  // 64KB: per-wave 16KB slice holding fp8 group (b*16 + mh*8 + w*2), pinned all steps
  __shared__ __align__(16) unsigned char Zlds[65536];
  __shared__ float aw[512];
  __shared__ float pS[4][32][16];
  __shared__ float red[8];
  const int bid = blockIdx.x, tid = threadIdx.x;
  const int lane = tid & 63, w = tid >> 6;
  const int al = lane & 15, kg = lane >> 4;

  f32x4 hreg = {0.f, 0.f, 0.f, 0.f};   // GRU h carry (blocks 384..511)

  // ---- one-time LDS fill: wave w pins group (b*16 + mh*8 + w*2) ----
  const int b2_ = bid >> 1, mh_ = bid & 1;
  {
    const unsigned char* src = P.Z8 + ((size_t)(b2_ * 16 + mh_ * 8 + w * 2) << 15)
                               + (size_t)lane * 16;
    unsigned char* dst = &Zlds[w * 16384 + lane * 16];
#pragma unroll
    for (int k = 0; k < 16; ++k) {
      uint4 v = *(const uint4*)(src + ((size_t)k << 10));
      *(uint4*)(dst + (k << 10)) = v;
    }
  }

  for (int t = 0; t < NT; ++t) {
    const int p = t & 1, np = p ^ 1;
    // ========== P1: logits[0,128) | gh[128,320) | idle[320,384) | gather[384,512) ==========
    if (bid < 128) {
      // logits = Lx[p] + h @ Wa2^T + b_attn : 32r x 32c tile, K=512
      int rt = bid >> 4, ct = bid & 15;
      int row0 = rt * 32 + (w & 1) * 16, col0 = ct * 32 + (w >> 1) * 16;
      const unsigned short* Ah = P.Hbf + (size_t)(row0 + al) * NH;
      const unsigned short* B = P.Wa + (size_t)(col0 + al) * 1024 + 512;
      uint4 fh[16];
      float lx[4];
#pragma unroll
      for (int i = 0; i < 16; ++i) ldg16(fh[i], Ah + i * 32 + kg * 8);
      {
        const float* lxp = P.Lx + (size_t)p * (NB * NI) + (size_t)(row0 + kg * 4) * NI + col0 + al;
#pragma unroll
        for (int r = 0; r < 4; ++r) ldg4(lx[r], lxp + (size_t)r * NI);
      }
      wait_vm0();
      f32x4 a1 = {0.f, 0.f, 0.f, 0.f};
#pragma unroll
      for (int i = 0; i < 16; ++i)
        a1 = MFMA(as_frag(fh[i]), *(const bf16x8*)(B + i * 32 + kg * 8), a1);
#pragma unroll
      for (int r = 0; r < 4; ++r) {
        int row = row0 + kg * 4 + r;
        stf(&P.logits[row * NI + col0 + al], lx[r] + a1[r] + P.b_attn[col0 + al]);
      }
      __syncthreads();
      if (tid == 0) flag_add(&P.bar[FLG_LOGIT(rt)]);
    } else if (bid < 320) {
      // gh = h @ Whh^T + b_hh : 64r x 32c
      int bb = bid - 128;
      int rt = bb / 48, ct = bb % 48;
      int row0 = rt * 64 + w * 16, col0 = ct * 32;
      const unsigned short* Ah = P.Hbf + (size_t)(row0 + al) * NH;
      const unsigned short* B0 = P.Whh + (size_t)(col0 + al) * 512;
      const unsigned short* B1 = P.Whh + (size_t)(col0 + 16 + al) * 512;
      uint4 fa[16];
#pragma unroll
      for (int i = 0; i < 16; ++i) ldg16(fa[i], Ah + i * 32 + kg * 8);
      wait_vm0();
      f32x4 a0 = {0.f, 0.f, 0.f, 0.f}, a1 = {0.f, 0.f, 0.f, 0.f};
#pragma unroll
      for (int i = 0; i < 16; ++i) {
        a0 = MFMA(as_frag(fa[i]), *(const bf16x8*)(B0 + i * 32 + kg * 8), a0);
        a1 = MFMA(as_frag(fa[i]), *(const bf16x8*)(B1 + i * 32 + kg * 8), a1);
      }
#pragma unroll
      for (int r = 0; r < 4; ++r) {
        int row = row0 + kg * 4 + r;
        stf(&P.gh[row * NG + col0 + al], a0[r] + P.b_hh[col0 + al]);
        stf(&P.gh[row * NG + col0 + 16 + al], a1[r] + P.b_hh[col0 + 16 + al]);
      }
      __syncthreads();
      if (tid == 0) flag_add(&P.bar[FLG_GH(rt)]);
    } else if (bid < 384) {
      // idle in P1; LxGx work happens in the P3 slot
    } else {
      // gather x_{t+1} into Xt[np]; flag for LxGx blocks
      if (t < NT - 1) {
        for (int e2 = (bid - 384) * 256 + tid; e2 < NB * NI / 2; e2 += 128 * 256) {
          int b = e2 >> 8, i = (e2 & 255) * 2;
          const float* xp = P.x + ((size_t)b * 512 + i) * 512 + t + 1;
          unsigned lo = f2bf(xp[0]);
          unsigned hi = f2bf(xp[512]);
          stu32(&P.Xt[(size_t)np * (NB * NI) + b * 512 + i], lo | (hi << 16));
        }
        __syncthreads();
        if (tid == 0) flag_add(&P.bar[FLG_XT]);
      }
    }

    // ========== P2: streamed-Zt ISSUE FIRST, then softmax, then consume ==========
    {
      const int b = b2_, mh = mh_;
      // hoisted: streamed group loads issued BEFORE the logits flag-wait; their
      // ~LLC/HBM service time overlaps P1-logits production + softmax.
      const unsigned char* Zb1 = P.Z8 + ((size_t)(b * 16 + mh * 8 + w * 2 + 1) << 15)
                                + (size_t)lane * 16;
      uint4 px[16];
#pragma unroll
      for (int k = 0; k < 16; ++k) ldg16p(px[k], Zb1 + ((size_t)k << 10));

      if (tid == 0) flag_wait(&P.bar[FLG_LOGIT(b >> 5)], 16u * (t + 1));
      __syncthreads();
      float2 lv;
      ldg8(lv, P.logits + (size_t)b * NI + 2 * tid);
      wait_vm0();   // drains lv AND the px burst (which had the flag-wait to land)
      float mx = fmaxf(lv.x, lv.y);
#pragma unroll
      for (int off = 32; off >= 1; off >>= 1) mx = fmaxf(mx, __shfl_xor(mx, off));
      if (lane == 0) red[w] = mx;
      __syncthreads();
      mx = fmaxf(fmaxf(red[0], red[1]), fmaxf(red[2], red[3]));
      float e0 = __expf(lv.x - mx), e1 = __expf(lv.y - mx);
      float sm = e0 + e1;
#pragma unroll
      for (int off = 32; off >= 1; off >>= 1) sm += __shfl_xor(sm, off);
      if (lane == 0) red[4 + w] = sm;
      __syncthreads();
      sm = (red[4] + red[5]) + (red[6] + red[7]);
      float inv = 1.f / sm;
      // fold per-row fp8 scale into aw
      float2 scl = *(const float2*)(P.Zsc + (size_t)b * 512 + 2 * tid);
      aw[2 * tid] = e0 * inv * scl.x;
      aw[2 * tid + 1] = e1 * inv * scl.y;
      __syncthreads();

      // wave w: group w*2 from LDS (pinned), group w*2+1 from the prefetched px.
      const int half = lane >> 5, hl = lane & 31;
      const float* awp = aw + mh * 256 + w * 64;
      float acc[16];
#pragma unroll
      for (int i = 0; i < 16; ++i) acc[i] = 0.f;
      // gg=0: LDS-pinned group
      const unsigned char* Zl = &Zlds[w * 16384 + lane * 16];
#pragma unroll
      for (int k = 0; k < 16; ++k) {
        uint4 pl = *(const uint4*)(Zl + (k << 10));
        float a_ = awp[2 * k + half];
        FP8_FMA16(pl, a_, acc);
      }
      // gg=1: prefetched streamed group
#pragma unroll
      for (int k = 0; k < 16; ++k) {
        float a_ = awp[32 + 2 * k + half];
        FP8_FMA16(px[k], a_, acc);
      }
      // fold lane-halves (same h-cols, different m-rows), then 4-wave LDS combine
#pragma unroll
      for (int i = 0; i < 16; ++i) acc[i] += __shfl_xor(acc[i], 32);
      if (lane < 32) {
#pragma unroll
        for (int i = 0; i < 16; ++i) pS[w][hl][i] = acc[i];
      }
      __syncthreads();
      const int c0 = 2 * tid, c1 = 2 * tid + 1;
      float s0 = (pS[0][c0 >> 4][c0 & 15] + pS[1][c0 >> 4][c0 & 15])
               + (pS[2][c0 >> 4][c0 & 15] + pS[3][c0 >> 4][c0 & 15]);
      float s1 = (pS[0][c1 >> 4][c1 & 15] + pS[1][c1 >> 4][c1 & 15])
               + (pS[2][c1 >> 4][c1 & 15] + pS[3][c1 >> 4][c1 & 15]);
      if (mh == 0) {
        union { float f[2]; unsigned long long q; } q0;
        q0.f[0] = s0; q0.f[1] = s1;
        stu64(&P.Gp[(size_t)b * NH + c0], q0.q);
        __syncthreads();
        if (tid == 0) flag_add(&P.bar[FLG_GP(b)]);
      } else {
        __syncthreads();
        if (tid == 0) flag_wait(&P.bar[FLG_GP(b)], (unsigned)(t + 1));
        __syncthreads();
        float2 gp2, gx2;
        ldg8(gp2, &P.Gp[(size_t)b * NH + c0]);
        ldg8(gx2, P.Gx + (size_t)p * (NB * NH) + (size_t)b * NH + c0);
        wait_vm0();
        float v0 = fmaxf(gx2.x + gp2.x + s0, 0.f);
        float v1 = fmaxf(gx2.y + gp2.y + s1, 0.f);
        stu32(&P.Gbf[(size_t)b * NH + c0], (unsigned)f2bf(v0) | ((unsigned)f2bf(v1) << 16));
        __syncthreads();
        if (tid == 0) flag_add(&P.bar[FLG_G(b >> 5)]);
      }
    }

    // ========== P3 slot: GRU [384,512) | next-step Lx/Gx [320,384) ==========
    if (bid >= 384) {
      int q = bid - 384;
      int rt = q >> 4, ct = q & 15;
      int row0 = rt * 32 + (w & 1) * 16;
      int j0 = ct * 32 + (w >> 1) * 16;
      if (tid == 0) {
        flag_wait(&P.bar[FLG_G(rt)], 32u * (t + 1));
        flag_wait(&P.bar[FLG_GH(rt >> 1)], 48u * (t + 1));
      }
      __syncthreads();
      const unsigned short* Ag = P.Gbf + (size_t)(row0 + al) * NH;
      const unsigned short* Br = P.Wih + (size_t)(j0 + al) * 512;
      const unsigned short* Bz = P.Wih + (size_t)(j0 + 512 + al) * 512;
      const unsigned short* Bn = P.Wih + (size_t)(j0 + 1024 + al) * 512;
      int j = j0 + al;
      uint4 fa[16];
      float ghv[4][3];
#pragma unroll
      for (int i = 0; i < 16; ++i) ldg16(fa[i], Ag + i * 32 + kg * 8);
#pragma unroll
      for (int r = 0; r < 4; ++r) {
        const float* ghrow = P.gh + (size_t)(row0 + kg * 4 + r) * NG + j;
        ldg4(ghv[r][0], ghrow);
        ldg4(ghv[r][1], ghrow + 512);
        ldg4(ghv[r][2], ghrow + 1024);
      }
      wait_vm0();
      f32x4 ar = {0.f, 0.f, 0.f, 0.f}, az = {0.f, 0.f, 0.f, 0.f}, an = {0.f, 0.f, 0.f, 0.f};
#pragma unroll
      for (int i = 0; i < 16; ++i) {
        ar = MFMA(as_frag(fa[i]), *(const bf16x8*)(Br + i * 32 + kg * 8), ar);
        az = MFMA(as_frag(fa[i]), *(const bf16x8*)(Bz + i * 32 + kg * 8), az);
        an = MFMA(as_frag(fa[i]), *(const bf16x8*)(Bn + i * 32 + kg * 8), an);
      }
      float bir = P.b_ih[j], biz = P.b_ih[j + 512], bin_ = P.b_ih[j + 1024];
#pragma unroll
      for (int r = 0; r < 4; ++r) {
        int row = row0 + kg * 4 + r;
        float rg = sigm(ar[r] + bir + ghv[r][0]);
        float zg = sigm(az[r] + biz + ghv[r][1]);
        float ng = tanhf(an[r] + bin_ + rg * ghv[r][2]);
        float hn = (1.f - zg) * ng + zg * hreg[r];
        hreg[r] = hn;
        unsigned hv = f2bf(hn);
        unsigned ov = __shfl_xor((int)hv, 1);
        if ((al & 1) == 0)
          stu32(&P.Hbf[(size_t)row * NH + (j & ~1)], hv | (ov << 16));
      }
    } else if (bid >= 320) {
      // Lx[np] = x_{t+1}@Wa1^T ; Gx[np] = x_{t+1}@Wc1^T + b_comb  (4 tiles/block)
      if (t < NT - 1) {
        if (tid == 0) flag_wait(&P.bar[FLG_XT], 128u * (t + 1));
        __syncthreads();
        int q = bid - 320;
        for (int jj = 0; jj < 4; ++jj) {
          int T = q + 64 * jj;
          int m = T >> 7, tt = T & 127;
          int rt = tt >> 4, ct = tt & 15;
          int row0 = rt * 32 + (w & 1) * 16, col0 = ct * 32 + (w >> 1) * 16;
          const unsigned short* A = P.Xt + (size_t)np * (NB * NI) + (size_t)(row0 + al) * NI;
          const unsigned short* B = (m ? P.Wc : P.Wa) + (size_t)(col0 + al) * 1024;
          uint4 fa[16];
#pragma unroll
          for (int i = 0; i < 16; ++i) ldg16(fa[i], A + i * 32 + kg * 8);
          wait_vm0();
          f32x4 acc = {0.f, 0.f, 0.f, 0.f};
#pragma unroll
          for (int i = 0; i < 16; ++i)
            acc = MFMA(as_frag(fa[i]), *(const bf16x8*)(B + i * 32 + kg * 8), acc);
          float* dst = (m ? P.Gx : P.Lx) + (size_t)np * (NB * NI);
          float bias = m ? P.b_comb[col0 + al] : 0.f;
#pragma unroll
          for (int r = 0; r < 4; ++r) {
            int row = row0 + kg * 4 + r;
            stf(&dst[row * NI + col0 + al], acc[r] + bias);
          }
        }
      }
    }
    gbar(P.bar, (unsigned)(t + 1));
  }

  // ========== epilogue: out = h_T @ Wout^T + b_out ==========
  if (bid < 128) {
    int rt = bid >> 4, ct = bid & 15;
    int row0 = rt * 32 + (w & 1) * 16;
    int col0 = ct * 32 + (w >> 1) * 16;
    const unsigned short* Ah = P.Hbf + (size_t)(row0 + al) * NH;
    const unsigned short* B0 = P.Wout + (size_t)(col0 + al) * 512;
    uint4 fa[16];
#pragma unroll
    for (int i = 0; i < 16; ++i) ldg16(fa[i], Ah + i * 32 + kg * 8);
    wait_vm0();
    f32x4 acc = {0.f, 0.f, 0.f, 0.f};
#pragma unroll
    for (int i = 0; i < 16; ++i) acc = MFMA(as_frag(fa[i]), *(const bf16x8*)(B0 + i * 32 + kg * 8), acc);
#pragma unroll
    for (int r = 0; r < 4; ++r) {
      int row = row0 + kg * 4 + r;
      P.out[row * 512 + col0 + al] = acc[r] + P.b_out[col0 + al];
    }
  }
}

extern "C" void kernel_launch(void* const* d_in, const int* in_sizes, int n_in,
                              void* d_out, int out_size, void* d_ws, size_t ws_size,
                              hipStream_t stream) {
  const float* x      = (const float*)d_in[0];
  const float* W_attn = (const float*)d_in[1];
  const float* b_attn = (const float*)d_in[2];
  const float* W_comb = (const float*)d_in[3];
  const float* b_comb = (const float*)d_in[4];
  const float* W_ih   = (const float*)d_in[5];
  const float* W_hh   = (const float*)d_in[6];
  const float* b_ih   = (const float*)d_in[7];
  const float* b_hh   = (const float*)d_in[8];
  const float* W_out  = (const float*)d_in[9];
  const float* b_out  = (const float*)d_in[10];

  char* wp = (char*)d_ws;
  size_t off = 0;
  unsigned short* XZ   = (unsigned short*)(wp + off); off += (size_t)NB * NI * NH * 2;   // 128MB
  unsigned short* Wa   = (unsigned short*)(wp + off); off += (size_t)NI * 1024 * 2;
  unsigned short* Whh  = (unsigned short*)(wp + off); off += (size_t)NG * 512 * 2;
  unsigned short* Wc   = (unsigned short*)(wp + off); off += (size_t)NH * 1024 * 2;
  unsigned short* Wih  = (unsigned short*)(wp + off); off += (size_t)NG * 512 * 2;
  unsigned short* Wout = (unsigned short*)(wp + off); off += (size_t)512 * 512 * 2;
  unsigned short* Xt   = (unsigned short*)(wp + off); off += (size_t)2 * NB * NI * 2;
  unsigned short* Hbf  = (unsigned short*)(wp + off); off += (size_t)NB * NH * 2;
  unsigned short* Gbf  = (unsigned short*)(wp + off); off += (size_t)NB * NH * 2;
  float* logits        = (float*)(wp + off); off += (size_t)NB * NI * 4;
  float* gh            = (float*)(wp + off); off += (size_t)NB * NG * 4;
  float* Lx            = (float*)(wp + off); off += (size_t)2 * NB * NI * 4;
  float* Gx            = (float*)(wp + off); off += (size_t)2 * NB * NI * 4;
  float* Gp            = (float*)(wp + off); off += (size_t)NB * NH * 4;
  float* Zsc           = (float*)(wp + off); off += (size_t)NB * NI * 4;   // 512KB scales
  unsigned* bar        = (unsigned*)(wp + off); off += (size_t)BAR_WORDS * 4 + 4096;

  cast_f32_bf16<<<8192, 256, 0, stream>>>(x, XZ, NB * NI * NT);
  cast_f32_bf16<<<512, 256, 0, stream>>>(W_attn, Wa, NI * 1024);
  cast_f32_bf16<<<512, 256, 0, stream>>>(W_hh, Whh, NG * 512);
  cast_f32_bf16<<<512, 256, 0, stream>>>(W_comb, Wc, NH * 1024);
  cast_f32_bf16<<<512, 256, 0, stream>>>(W_ih, Wih, NG * 512);
  cast_f32_bf16<<<512, 256, 0, stream>>>(W_out, Wout, 512 * 512);
  zt_fp8<<<4096, 256, 0, stream>>>(XZ, Zsc, Wc);
  init_kernel<<<512, 256, 0, stream>>>(x, Xt, Hbf, bar);
  lxgx0_kernel<<<256, 256, 0, stream>>>(Xt, Wa, Wc, b_comb, Lx, Gx);

  KParams prm;
  prm.Z8 = (const unsigned char*)XZ; prm.Zsc = Zsc;
  prm.Wa = Wa; prm.Whh = Whh; prm.Wc = Wc; prm.Wih = Wih; prm.Wout = Wout;
  prm.Xt = Xt; prm.Hbf = Hbf; prm.Gbf = Gbf;
  prm.logits = logits; prm.gh = gh; prm.Lx = Lx; prm.Gx = Gx; prm.Gp = Gp;
  prm.x = x; prm.b_attn = b_attn; prm.b_hh = b_hh; prm.b_ih = b_ih; prm.b_out = b_out;
  prm.b_comb = b_comb;
  prm.out = (float*)d_out;
  prm.bar = bar;

  void* kargs[] = { &prm };
  hipError_t e = hipLaunchCooperativeKernel((const void*)persistent_kernel,
                                            dim3(NBLK), dim3(256), kargs, 0, stream);
  if (e != hipSuccess) {
    persistent_kernel<<<dim3(NBLK), dim3(256), 0, stream>>>(prm);
  }
}

// Round 15
// 26924.249 us; speedup vs baseline: 1.3506x; 1.1004x over previous
//
#include <hip/hip_runtime.h>

#define NB 256    // batch
#define NT 512    // T == MAXLEN
#define NI 512    // INPUTS == M
#define NH 512    // HIDDEN
#define NG 1536   // 3*H
#define NBLK 512  // persistent grid

typedef __attribute__((ext_vector_type(8))) short bf16x8;
typedef __attribute__((ext_vector_type(4))) float f32x4;
typedef __attribute__((ext_vector_type(2))) float f32x2;

#define MFMA(a, b, c) __builtin_amdgcn_mfma_f32_16x16x32_bf16((a), (b), (c), 0, 0, 0)

// barrier/flag word offsets inside bar[] (each flag on its own 256B line)
#define BAR_LEAF(g)   ((g) * 64)           // g<16, +32/step each
#define BAR_ROOT      1024                 // +16/step
#define BAR_GEN       1088                 // +1/step
#define FLG_LOGIT(rt) (1152 + (rt) * 64)   // rt<8,  target 16*(t+1)
#define FLG_GH(rt)    (1664 + (rt) * 64)   // rt<4,  target 48*(t+1)
#define FLG_XT        1920                 // target 128*(t+1)
#define FLG_G(rg)     (2176 + (rg) * 64)   // rg<8,  target 32*(t+1)
#define FLG_GP(b)     (2688 + (b) * 64)    // b<256, target (t+1)
#define BAR_WORDS     20480

__device__ __forceinline__ unsigned short f2bf(float f) {
  unsigned int u = __float_as_uint(f);
  u = u + 0x7FFFu + ((u >> 16) & 1u);
  return (unsigned short)(u >> 16);
}
__device__ __forceinline__ float sigm(float x) { return 1.f / (1.f + __expf(-x)); }

// ---- sc1 (agent-coherent, LLC) stores via relaxed atomics ----
__device__ __forceinline__ void stf(float* p, float v) {
  __hip_atomic_store(p, v, __ATOMIC_RELAXED, __HIP_MEMORY_SCOPE_AGENT);
}
__device__ __forceinline__ void stu32(void* p, unsigned v) {
  __hip_atomic_store((unsigned*)p, v, __ATOMIC_RELAXED, __HIP_MEMORY_SCOPE_AGENT);
}
__device__ __forceinline__ void stu64(void* p, unsigned long long v) {
  __hip_atomic_store((unsigned long long*)p, v, __ATOMIC_RELAXED, __HIP_MEMORY_SCOPE_AGENT);
}
// ---- pipelined LOADS via inline asm (batched; one waitcnt per burst) ----
__device__ __forceinline__ void ldg16(uint4& d, const void* p) {
  asm volatile("global_load_dwordx4 %0, %1, off sc1" : "=v"(d) : "v"(p));
}
__device__ __forceinline__ void ldg8(float2& d, const void* p) {
  asm volatile("global_load_dwordx2 %0, %1, off sc1" : "=v"(d) : "v"(p));
}
__device__ __forceinline__ void ldg4(float& d, const void* p) {
  asm volatile("global_load_dword %0, %1, off sc1" : "=v"(d) : "v"(p));
}
__device__ __forceinline__ void wait_vm0() {
  asm volatile("s_waitcnt vmcnt(0)" ::: "memory");
  __builtin_amdgcn_sched_barrier(0);   // rule #18
}
__device__ __forceinline__ bf16x8 as_frag(uint4 v) {
  union { uint4 u; bf16x8 f; } c; c.u = v; return c.f;
}

// ---- monotonic relaxed flags ----
__device__ __forceinline__ void flag_add(unsigned* f) {
  __hip_atomic_fetch_add(f, 1u, __ATOMIC_RELAXED, __HIP_MEMORY_SCOPE_AGENT);
}
__device__ __forceinline__ void flag_wait(unsigned* f, unsigned target) {
  while (__hip_atomic_load(f, __ATOMIC_RELAXED, __HIP_MEMORY_SCOPE_AGENT) < target)
    __builtin_amdgcn_s_sleep(1);
}

// 8x cvt + 16x fma on one uint4 of 16 fp8 values
#define FP8_FMA16(PX, A_, ACC) do {                                              \
    f32x2 d0 = __builtin_amdgcn_cvt_pk_f32_fp8((int)(PX).x, false);              \
    f32x2 d1 = __builtin_amdgcn_cvt_pk_f32_fp8((int)(PX).x, true);               \
    f32x2 d2 = __builtin_amdgcn_cvt_pk_f32_fp8((int)(PX).y, false);              \
    f32x2 d3 = __builtin_amdgcn_cvt_pk_f32_fp8((int)(PX).y, true);               \
    f32x2 d4 = __builtin_amdgcn_cvt_pk_f32_fp8((int)(PX).z, false);              \
    f32x2 d5 = __builtin_amdgcn_cvt_pk_f32_fp8((int)(PX).z, true);               \
    f32x2 d6 = __builtin_amdgcn_cvt_pk_f32_fp8((int)(PX).w, false);              \
    f32x2 d7 = __builtin_amdgcn_cvt_pk_f32_fp8((int)(PX).w, true);               \
    (ACC)[0]  = fmaf((A_), d0[0], (ACC)[0]);  (ACC)[1]  = fmaf((A_), d0[1], (ACC)[1]);  \
    (ACC)[2]  = fmaf((A_), d1[0], (ACC)[2]);  (ACC)[3]  = fmaf((A_), d1[1], (ACC)[3]);  \
    (ACC)[4]  = fmaf((A_), d2[0], (ACC)[4]);  (ACC)[5]  = fmaf((A_), d2[1], (ACC)[5]);  \
    (ACC)[6]  = fmaf((A_), d3[0], (ACC)[6]);  (ACC)[7]  = fmaf((A_), d3[1], (ACC)[7]);  \
    (ACC)[8]  = fmaf((A_), d4[0], (ACC)[8]);  (ACC)[9]  = fmaf((A_), d4[1], (ACC)[9]);  \
    (ACC)[10] = fmaf((A_), d5[0], (ACC)[10]); (ACC)[11] = fmaf((A_), d5[1], (ACC)[11]); \
    (ACC)[12] = fmaf((A_), d6[0], (ACC)[12]); (ACC)[13] = fmaf((A_), d6[1], (ACC)[13]); \
    (ACC)[14] = fmaf((A_), d7[0], (ACC)[14]); (ACC)[15] = fmaf((A_), d7[1], (ACC)[15]); \
  } while (0)

// ---------------- generic f32 -> bf16 cast ----------------
__global__ __launch_bounds__(256) void cast_f32_bf16(const float* __restrict__ s,
                                                     unsigned short* __restrict__ d, int n) {
  int i = blockIdx.x * 256 + threadIdx.x;
  int stride = gridDim.x * 256;
  for (; i < n; i += stride) d[i] = f2bf(s[i]);
}

// ---------------- Zt = (bf16 X) @ Wc2^T -> fp8 DENSE-PACKED + per-row scale ----------------
__global__ __launch_bounds__(256) void zt_fp8(unsigned short* __restrict__ XZ,
                                              float* __restrict__ Zsc,
                                              const unsigned short* __restrict__ Wc) {
  __shared__ unsigned short As[32][552];
  __shared__ float Zf[32][512];
  const int tid = threadIdx.x;
  const int row0 = blockIdx.x * 32;
  const uint4* src = (const uint4*)(XZ + (size_t)row0 * 512);
#pragma unroll
  for (int it = 0; it < 8; ++it) {
    int e8 = tid + it * 256;
    uint4 v = src[e8];
    *(uint4*)&As[e8 >> 6][(e8 & 63) * 8] = v;
  }
  __syncthreads();
  const int lane = tid & 63, w = tid >> 6;
  const int al = lane & 15, kg = lane >> 4;
  const int rbase = (w & 1) * 16;
  const int cbase = (w >> 1) * 256;
  for (int cc = 0; cc < 16; ++cc) {
    int col0 = cbase + cc * 16;
    f32x4 acc = {0.f, 0.f, 0.f, 0.f};
    const unsigned short* Bp = Wc + (size_t)(col0 + al) * 1024 + 512;
    for (int k = 0; k < 512; k += 32) {
      bf16x8 av = *(const bf16x8*)&As[rbase + al][k + kg * 8];
      bf16x8 bv = *(const bf16x8*)(Bp + k + kg * 8);
      acc = MFMA(av, bv, acc);
    }
#pragma unroll
    for (int r = 0; r < 4; ++r)
      Zf[rbase + kg * 4 + r][col0 + al] = acc[r];
  }
  __syncthreads();
  unsigned char* Z8 = (unsigned char*)XZ + ((size_t)blockIdx.x << 15);
#pragma unroll 2
  for (int r8 = 0; r8 < 8; ++r8) {
    int row = w * 8 + r8;
    const float* vr = &Zf[row][lane * 8];
    float v0 = vr[0], v1 = vr[1], v2 = vr[2], v3 = vr[3];
    float v4 = vr[4], v5 = vr[5], v6 = vr[6], v7 = vr[7];
    float amax = fmaxf(fmaxf(fmaxf(fabsf(v0), fabsf(v1)), fmaxf(fabsf(v2), fabsf(v3))),
                       fmaxf(fmaxf(fabsf(v4), fabsf(v5)), fmaxf(fabsf(v6), fabsf(v7))));
#pragma unroll
    for (int off = 32; off >= 1; off >>= 1) amax = fmaxf(amax, __shfl_xor(amax, off));
    float inv = amax > 0.f ? 448.f / amax : 0.f;
    int w0 = __builtin_amdgcn_cvt_pk_fp8_f32(v0 * inv, v1 * inv, 0, false);
    w0 = __builtin_amdgcn_cvt_pk_fp8_f32(v2 * inv, v3 * inv, w0, true);
    int w1 = __builtin_amdgcn_cvt_pk_fp8_f32(v4 * inv, v5 * inv, 0, false);
    w1 = __builtin_amdgcn_cvt_pk_fp8_f32(v6 * inv, v7 * inv, w1, true);
    uint2 o; o.x = (unsigned)w0; o.y = (unsigned)w1;
    *(uint2*)(Z8 + ((size_t)row << 9) + lane * 8) = o;
    if (lane == 0) Zsc[row0 + row] = amax * (1.f / 448.f);
  }
}

// ---------------- init: Xt[0] = x_0 gather, Hbf = 0, bar = 0 ----------------
__global__ __launch_bounds__(256) void init_kernel(const float* __restrict__ x,
                                                   unsigned short* __restrict__ Xt,
                                                   unsigned short* __restrict__ Hbf,
                                                   unsigned* __restrict__ bar) {
  int idx = blockIdx.x * 256 + threadIdx.x;
  if (idx < BAR_WORDS) bar[idx] = 0u;
  if (idx < NB * NI) {
    int b = idx >> 9, i = idx & 511;
    Xt[idx] = f2bf(x[((size_t)b * 512 + i) * 512]);
    Hbf[idx] = 0;
  }
}

// ---------------- prologue: Lx[0] = x_0@Wa1^T ; Gx[0] = x_0@Wc1^T + b_comb ----------------
__global__ __launch_bounds__(256) void lxgx0_kernel(const unsigned short* __restrict__ Xt0,
                                                    const unsigned short* __restrict__ Wa,
                                                    const unsigned short* __restrict__ Wc,
                                                    const float* __restrict__ b_comb,
                                                    float* __restrict__ Lx,
                                                    float* __restrict__ Gx) {
  const int tid = threadIdx.x, lane = tid & 63, w = tid >> 6;
  const int al = lane & 15, kg = lane >> 4;
  int T = blockIdx.x;                 // 256 tiles: [0,128) Lx, [128,256) Gx
  int m = T >> 7, tt = T & 127;
  int rt = tt >> 4, ct = tt & 15;
  int row0 = rt * 32 + (w & 1) * 16, col0 = ct * 32 + (w >> 1) * 16;
  const unsigned short* A = Xt0 + (size_t)(row0 + al) * NI;
  const unsigned short* B = (m ? Wc : Wa) + (size_t)(col0 + al) * 1024;
  f32x4 acc = {0.f, 0.f, 0.f, 0.f};
  for (int k = 0; k < 512; k += 32)
    acc = MFMA(*(const bf16x8*)(A + k + kg * 8), *(const bf16x8*)(B + k + kg * 8), acc);
  float* dst = m ? Gx : Lx;
  float bias = m ? b_comb[col0 + al] : 0.f;
#pragma unroll
  for (int r = 0; r < 4; ++r) {
    int row = row0 + kg * 4 + r;
    dst[row * NI + col0 + al] = acc[r] + bias;
  }
}

struct KParams {
  const unsigned char* Z8;    // fp8 Zt: group g (32 rows) dense 16KB at byte g<<15
  const float* Zsc;           // per-row scales [256*512]
  const unsigned short* Wa;   // [512][1024]
  const unsigned short* Whh;  // [1536][512]
  const unsigned short* Wc;   // [512][1024]
  const unsigned short* Wih;  // [1536][512]
  const unsigned short* Wout; // [512][512]
  unsigned short* Xt;         // [2][256][512] bf16 (cc) - gather target
  unsigned short* Hbf;        // [256][512] bf16 h (cc)
  unsigned short* Gbf;        // [256][512] bf16 g (cc)
  float* logits;              // [256][512] (cc)
  float* gh;                  // [256][1536] (cc)
  float* Lx;                  // [2][256][512] f32 x_t@Wa1^T (cc)
  float* Gx;                  // [2][256][512] f32 x_t@Wc1^T + b_comb (cc)
  float* Gp;                  // [256][512] f32 partial ctx (cc)
  const float* x;
  const float* b_attn;
  const float* b_hh;
  const float* b_ih;
  const float* b_comb;
  const float* b_out;
  float* out;
  unsigned* bar;
};

// single per-step global barrier: 16 leaves x 32 blocks -> root(16) -> gen
__device__ __forceinline__ void gbar(unsigned* bar, unsigned gen_expect) {
  asm volatile("s_waitcnt vmcnt(0)" ::: "memory");
  __syncthreads();
  if (threadIdx.x == 0) {
    unsigned old = __hip_atomic_fetch_add(&bar[BAR_LEAF(blockIdx.x >> 5)], 1u,
                                          __ATOMIC_RELAXED, __HIP_MEMORY_SCOPE_AGENT);
    if ((old & 31) == 31) {
      unsigned ro = __hip_atomic_fetch_add(&bar[BAR_ROOT], 1u,
                                           __ATOMIC_RELAXED, __HIP_MEMORY_SCOPE_AGENT);
      if ((ro & 15) == 15)
        __hip_atomic_fetch_add(&bar[BAR_GEN], 1u,
                               __ATOMIC_RELAXED, __HIP_MEMORY_SCOPE_AGENT);
    }
    while (__hip_atomic_load(&bar[BAR_GEN], __ATOMIC_RELAXED, __HIP_MEMORY_SCOPE_AGENT) < gen_expect)
      __builtin_amdgcn_s_sleep(2);
    asm volatile("" ::: "memory");
  }
  __syncthreads();
}

__global__ __launch_bounds__(256, 2) void persistent_kernel(KParams P) {
  // 64KB: per-wave 16KB slice holding fp8 group (b*16 + mh*8 + w*2), pinned all steps
  __shared__ __align__(16) unsigned char Zlds[65536];
  __shared__ float aw[512];
  __shared__ float pS[4][32][16];
  __shared__ float red[8];
  const int bid = blockIdx.x, tid = threadIdx.x;
  const int lane = tid & 63, w = tid >> 6;
  const int al = lane & 15, kg = lane >> 4;

  f32x4 hreg = {0.f, 0.f, 0.f, 0.f};   // GRU h carry (blocks 384..511)

  // ---- one-time LDS fill: wave w pins group (b*16 + mh*8 + w*2) ----
  const int b2_ = bid >> 1, mh_ = bid & 1;
  {
    const unsigned char* src = P.Z8 + ((size_t)(b2_ * 16 + mh_ * 8 + w * 2) << 15)
                               + (size_t)lane * 16;
    unsigned char* dst = &Zlds[w * 16384 + lane * 16];
#pragma unroll
    for (int k = 0; k < 16; ++k) {
      uint4 v = *(const uint4*)(src + ((size_t)k << 10));
      *(uint4*)(dst + (k << 10)) = v;
    }
  }
  // ---- one-time REGISTER pin: wave w holds group (b*16 + mh*8 + w*2 + 1) for all steps
  uint4 px[16];
  {
    const unsigned char* Zb1 = P.Z8 + ((size_t)(b2_ * 16 + mh_ * 8 + w * 2 + 1) << 15)
                              + (size_t)lane * 16;
#pragma unroll
    for (int k = 0; k < 16; ++k) px[k] = *(const uint4*)(Zb1 + ((size_t)k << 10));
  }

  for (int t = 0; t < NT; ++t) {
    const int p = t & 1, np = p ^ 1;
    // ========== P1: logits[0,128) | gh[128,320) | idle[320,384) | gather[384,512) ==========
    if (bid < 128) {
      // logits = Lx[p] + h @ Wa2^T + b_attn : 32r x 32c tile, K=512
      int rt = bid >> 4, ct = bid & 15;
      int row0 = rt * 32 + (w & 1) * 16, col0 = ct * 32 + (w >> 1) * 16;
      const unsigned short* Ah = P.Hbf + (size_t)(row0 + al) * NH;
      const unsigned short* B = P.Wa + (size_t)(col0 + al) * 1024 + 512;
      uint4 fh[16];
      float lx[4];
#pragma unroll
      for (int i = 0; i < 16; ++i) ldg16(fh[i], Ah + i * 32 + kg * 8);
      {
        const float* lxp = P.Lx + (size_t)p * (NB * NI) + (size_t)(row0 + kg * 4) * NI + col0 + al;
#pragma unroll
        for (int r = 0; r < 4; ++r) ldg4(lx[r], lxp + (size_t)r * NI);
      }
      wait_vm0();
      f32x4 a1 = {0.f, 0.f, 0.f, 0.f};
#pragma unroll
      for (int i = 0; i < 16; ++i)
        a1 = MFMA(as_frag(fh[i]), *(const bf16x8*)(B + i * 32 + kg * 8), a1);
#pragma unroll
      for (int r = 0; r < 4; ++r) {
        int row = row0 + kg * 4 + r;
        stf(&P.logits[row * NI + col0 + al], lx[r] + a1[r] + P.b_attn[col0 + al]);
      }
      __syncthreads();
      if (tid == 0) flag_add(&P.bar[FLG_LOGIT(rt)]);
    } else if (bid < 320) {
      // gh = h @ Whh^T + b_hh : 64r x 32c
      int bb = bid - 128;
      int rt = bb / 48, ct = bb % 48;
      int row0 = rt * 64 + w * 16, col0 = ct * 32;
      const unsigned short* Ah = P.Hbf + (size_t)(row0 + al) * NH;
      const unsigned short* B0 = P.Whh + (size_t)(col0 + al) * 512;
      const unsigned short* B1 = P.Whh + (size_t)(col0 + 16 + al) * 512;
      uint4 fa[16];
#pragma unroll
      for (int i = 0; i < 16; ++i) ldg16(fa[i], Ah + i * 32 + kg * 8);
      wait_vm0();
      f32x4 a0 = {0.f, 0.f, 0.f, 0.f}, a1 = {0.f, 0.f, 0.f, 0.f};
#pragma unroll
      for (int i = 0; i < 16; ++i) {
        a0 = MFMA(as_frag(fa[i]), *(const bf16x8*)(B0 + i * 32 + kg * 8), a0);
        a1 = MFMA(as_frag(fa[i]), *(const bf16x8*)(B1 + i * 32 + kg * 8), a1);
      }
#pragma unroll
      for (int r = 0; r < 4; ++r) {
        int row = row0 + kg * 4 + r;
        stf(&P.gh[row * NG + col0 + al], a0[r] + P.b_hh[col0 + al]);
        stf(&P.gh[row * NG + col0 + 16 + al], a1[r] + P.b_hh[col0 + 16 + al]);
      }
      __syncthreads();
      if (tid == 0) flag_add(&P.bar[FLG_GH(rt)]);
    } else if (bid < 384) {
      // idle in P1; LxGx work happens in the P3 slot
    } else {
      // gather x_{t+1} into Xt[np]; flag for LxGx blocks
      if (t < NT - 1) {
        for (int e2 = (bid - 384) * 256 + tid; e2 < NB * NI / 2; e2 += 128 * 256) {
          int b = e2 >> 8, i = (e2 & 255) * 2;
          const float* xp = P.x + ((size_t)b * 512 + i) * 512 + t + 1;
          unsigned lo = f2bf(xp[0]);
          unsigned hi = f2bf(xp[512]);
          stu32(&P.Xt[(size_t)np * (NB * NI) + b * 512 + i], lo | (hi << 16));
        }
        __syncthreads();
        if (tid == 0) flag_add(&P.bar[FLG_XT]);
      }
    }

    // ========== P2: softmax (+scale fold) + LDS-pinned + REG-pinned fp8 Zt ==========
    {
      const int b = b2_, mh = mh_;
      if (tid == 0) flag_wait(&P.bar[FLG_LOGIT(b >> 5)], 16u * (t + 1));
      __syncthreads();
      float2 lv;
      ldg8(lv, P.logits + (size_t)b * NI + 2 * tid);
      wait_vm0();
      float mx = fmaxf(lv.x, lv.y);
#pragma unroll
      for (int off = 32; off >= 1; off >>= 1) mx = fmaxf(mx, __shfl_xor(mx, off));
      if (lane == 0) red[w] = mx;
      __syncthreads();
      mx = fmaxf(fmaxf(red[0], red[1]), fmaxf(red[2], red[3]));
      float e0 = __expf(lv.x - mx), e1 = __expf(lv.y - mx);
      float sm = e0 + e1;
#pragma unroll
      for (int off = 32; off >= 1; off >>= 1) sm += __shfl_xor(sm, off);
      if (lane == 0) red[4 + w] = sm;
      __syncthreads();
      sm = (red[4] + red[5]) + (red[6] + red[7]);
      float inv = 1.f / sm;
      // fold per-row fp8 scale into aw
      float2 scl = *(const float2*)(P.Zsc + (size_t)b * 512 + 2 * tid);
      aw[2 * tid] = e0 * inv * scl.x;
      aw[2 * tid + 1] = e1 * inv * scl.y;
      __syncthreads();

      // wave w: group w*2 from LDS (pinned), group w*2+1 from registers (pinned).
      const int half = lane >> 5, hl = lane & 31;
      const float* awp = aw + mh * 256 + w * 64;
      float acc[16];
#pragma unroll
      for (int i = 0; i < 16; ++i) acc[i] = 0.f;
      // gg=0: LDS-pinned group
      const unsigned char* Zl = &Zlds[w * 16384 + lane * 16];
#pragma unroll
      for (int k = 0; k < 16; ++k) {
        uint4 pl = *(const uint4*)(Zl + (k << 10));
        float a_ = awp[2 * k + half];
        FP8_FMA16(pl, a_, acc);
      }
      // gg=1: register-pinned group
#pragma unroll
      for (int k = 0; k < 16; ++k) {
        float a_ = awp[32 + 2 * k + half];
        FP8_FMA16(px[k], a_, acc);
      }
      // fold lane-halves (same h-cols, different m-rows), then 4-wave LDS combine
#pragma unroll
      for (int i = 0; i < 16; ++i) acc[i] += __shfl_xor(acc[i], 32);
      if (lane < 32) {
#pragma unroll
        for (int i = 0; i < 16; ++i) pS[w][hl][i] = acc[i];
      }
      __syncthreads();
      const int c0 = 2 * tid, c1 = 2 * tid + 1;
      float s0 = (pS[0][c0 >> 4][c0 & 15] + pS[1][c0 >> 4][c0 & 15])
               + (pS[2][c0 >> 4][c0 & 15] + pS[3][c0 >> 4][c0 & 15]);
      float s1 = (pS[0][c1 >> 4][c1 & 15] + pS[1][c1 >> 4][c1 & 15])
               + (pS[2][c1 >> 4][c1 & 15] + pS[3][c1 >> 4][c1 & 15]);
      if (mh == 0) {
        union { float f[2]; unsigned long long q; } q0;
        q0.f[0] = s0; q0.f[1] = s1;
        stu64(&P.Gp[(size_t)b * NH + c0], q0.q);
        __syncthreads();
        if (tid == 0) flag_add(&P.bar[FLG_GP(b)]);
      } else {
        __syncthreads();
        if (tid == 0) flag_wait(&P.bar[FLG_GP(b)], (unsigned)(t + 1));
        __syncthreads();
        float2 gp2, gx2;
        ldg8(gp2, &P.Gp[(size_t)b * NH + c0]);
        ldg8(gx2, P.Gx + (size_t)p * (NB * NH) + (size_t)b * NH + c0);
        wait_vm0();
        float v0 = fmaxf(gx2.x + gp2.x + s0, 0.f);
        float v1 = fmaxf(gx2.y + gp2.y + s1, 0.f);
        stu32(&P.Gbf[(size_t)b * NH + c0], (unsigned)f2bf(v0) | ((unsigned)f2bf(v1) << 16));
        __syncthreads();
        if (tid == 0) flag_add(&P.bar[FLG_G(b >> 5)]);
      }
    }

    // ========== P3 slot: GRU [384,512) | next-step Lx/Gx [320,384) ==========
    if (bid >= 384) {
      int q = bid - 384;
      int rt = q >> 4, ct = q & 15;
      int row0 = rt * 32 + (w & 1) * 16;
      int j0 = ct * 32 + (w >> 1) * 16;
      if (tid == 0) {
        flag_wait(&P.bar[FLG_G(rt)], 32u * (t + 1));
        flag_wait(&P.bar[FLG_GH(rt >> 1)], 48u * (t + 1));
      }
      __syncthreads();
      const unsigned short* Ag = P.Gbf + (size_t)(row0 + al) * NH;
      const unsigned short* Br = P.Wih + (size_t)(j0 + al) * 512;
      const unsigned short* Bz = P.Wih + (size_t)(j0 + 512 + al) * 512;
      const unsigned short* Bn = P.Wih + (size_t)(j0 + 1024 + al) * 512;
      int j = j0 + al;
      uint4 fa[16];
      float ghv[4][3];
#pragma unroll
      for (int i = 0; i < 16; ++i) ldg16(fa[i], Ag + i * 32 + kg * 8);
#pragma unroll
      for (int r = 0; r < 4; ++r) {
        const float* ghrow = P.gh + (size_t)(row0 + kg * 4 + r) * NG + j;
        ldg4(ghv[r][0], ghrow);
        ldg4(ghv[r][1], ghrow + 512);
        ldg4(ghv[r][2], ghrow + 1024);
      }
      wait_vm0();
      f32x4 ar = {0.f, 0.f, 0.f, 0.f}, az = {0.f, 0.f, 0.f, 0.f}, an = {0.f, 0.f, 0.f, 0.f};
#pragma unroll
      for (int i = 0; i < 16; ++i) {
        ar = MFMA(as_frag(fa[i]), *(const bf16x8*)(Br + i * 32 + kg * 8), ar);
        az = MFMA(as_frag(fa[i]), *(const bf16x8*)(Bz + i * 32 + kg * 8), az);
        an = MFMA(as_frag(fa[i]), *(const bf16x8*)(Bn + i * 32 + kg * 8), an);
      }
      float bir = P.b_ih[j], biz = P.b_ih[j + 512], bin_ = P.b_ih[j + 1024];
#pragma unroll
      for (int r = 0; r < 4; ++r) {
        int row = row0 + kg * 4 + r;
        float rg = sigm(ar[r] + bir + ghv[r][0]);
        float zg = sigm(az[r] + biz + ghv[r][1]);
        float ng = tanhf(an[r] + bin_ + rg * ghv[r][2]);
        float hn = (1.f - zg) * ng + zg * hreg[r];
        hreg[r] = hn;
        unsigned hv = f2bf(hn);
        unsigned ov = __shfl_xor((int)hv, 1);
        if ((al & 1) == 0)
          stu32(&P.Hbf[(size_t)row * NH + (j & ~1)], hv | (ov << 16));
      }
    } else if (bid >= 320) {
      // Lx[np] = x_{t+1}@Wa1^T ; Gx[np] = x_{t+1}@Wc1^T + b_comb  (4 tiles/block)
      if (t < NT - 1) {
        if (tid == 0) flag_wait(&P.bar[FLG_XT], 128u * (t + 1));
        __syncthreads();
        int q = bid - 320;
        for (int jj = 0; jj < 4; ++jj) {
          int T = q + 64 * jj;
          int m = T >> 7, tt = T & 127;
          int rt = tt >> 4, ct = tt & 15;
          int row0 = rt * 32 + (w & 1) * 16, col0 = ct * 32 + (w >> 1) * 16;
          const unsigned short* A = P.Xt + (size_t)np * (NB * NI) + (size_t)(row0 + al) * NI;
          const unsigned short* B = (m ? P.Wc : P.Wa) + (size_t)(col0 + al) * 1024;
          uint4 fa[16];
#pragma unroll
          for (int i = 0; i < 16; ++i) ldg16(fa[i], A + i * 32 + kg * 8);
          wait_vm0();
          f32x4 acc = {0.f, 0.f, 0.f, 0.f};
#pragma unroll
          for (int i = 0; i < 16; ++i)
            acc = MFMA(as_frag(fa[i]), *(const bf16x8*)(B + i * 32 + kg * 8), acc);
          float* dst = (m ? P.Gx : P.Lx) + (size_t)np * (NB * NI);
          float bias = m ? P.b_comb[col0 + al] : 0.f;
#pragma unroll
          for (int r = 0; r < 4; ++r) {
            int row = row0 + kg * 4 + r;
            stf(&dst[row * NI + col0 + al], acc[r] + bias);
          }
        }
      }
    }
    gbar(P.bar, (unsigned)(t + 1));
  }

  // ========== epilogue: out = h_T @ Wout^T + b_out ==========
  if (bid < 128) {
    int rt = bid >> 4, ct = bid & 15;
    int row0 = rt * 32 + (w & 1) * 16;
    int col0 = ct * 32 + (w >> 1) * 16;
    const unsigned short* Ah = P.Hbf + (size_t)(row0 + al) * NH;
    const unsigned short* B0 = P.Wout + (size_t)(col0 + al) * 512;
    uint4 fa[16];
#pragma unroll
    for (int i = 0; i < 16; ++i) ldg16(fa[i], Ah + i * 32 + kg * 8);
    wait_vm0();
    f32x4 acc = {0.f, 0.f, 0.f, 0.f};
#pragma unroll
    for (int i = 0; i < 16; ++i) acc = MFMA(as_frag(fa[i]), *(const bf16x8*)(B0 + i * 32 + kg * 8), acc);
#pragma unroll
    for (int r = 0; r < 4; ++r) {
      int row = row0 + kg * 4 + r;
      P.out[row * 512 + col0 + al] = acc[r] + P.b_out[col0 + al];
    }
  }
}

extern "C" void kernel_launch(void* const* d_in, const int* in_sizes, int n_in,
                              void* d_out, int out_size, void* d_ws, size_t ws_size,
                              hipStream_t stream) {
  const float* x      = (const float*)d_in[0];
  const float* W_attn = (const float*)d_in[1];
  const float* b_attn = (const float*)d_in[2];
  const float* W_comb = (const float*)d_in[3];
  const float* b_comb = (const float*)d_in[4];
  const float* W_ih   = (const float*)d_in[5];
  const float* W_hh   = (const float*)d_in[6];
  const float* b_ih   = (const float*)d_in[7];
  const float* b_hh   = (const float*)d_in[8];
  const float* W_out  = (const float*)d_in[9];
  const float* b_out  = (const float*)d_in[10];

  char* wp = (char*)d_ws;
  size_t off = 0;
  unsigned short* XZ   = (unsigned short*)(wp + off); off += (size_t)NB * NI * NH * 2;   // 128MB
  unsigned short* Wa   = (unsigned short*)(wp + off); off += (size_t)NI * 1024 * 2;
  unsigned short* Whh  = (unsigned short*)(wp + off); off += (size_t)NG * 512 * 2;
  unsigned short* Wc   = (unsigned short*)(wp + off); off += (size_t)NH * 1024 * 2;
  unsigned short* Wih  = (unsigned short*)(wp + off); off += (size_t)NG * 512 * 2;
  unsigned short* Wout = (unsigned short*)(wp + off); off += (size_t)512 * 512 * 2;
  unsigned short* Xt   = (unsigned short*)(wp + off); off += (size_t)2 * NB * NI * 2;
  unsigned short* Hbf  = (unsigned short*)(wp + off); off += (size_t)NB * NH * 2;
  unsigned short* Gbf  = (unsigned short*)(wp + off); off += (size_t)NB * NH * 2;
  float* logits        = (float*)(wp + off); off += (size_t)NB * NI * 4;
  float* gh            = (float*)(wp + off); off += (size_t)NB * NG * 4;
  float* Lx            = (float*)(wp + off); off += (size_t)2 * NB * NI * 4;
  float* Gx            = (float*)(wp + off); off += (size_t)2 * NB * NI * 4;
  float* Gp            = (float*)(wp + off); off += (size_t)NB * NH * 4;
  float* Zsc           = (float*)(wp + off); off += (size_t)NB * NI * 4;   // 512KB scales
  unsigned* bar        = (unsigned*)(wp + off); off += (size_t)BAR_WORDS * 4 + 4096;

  cast_f32_bf16<<<8192, 256, 0, stream>>>(x, XZ, NB * NI * NT);
  cast_f32_bf16<<<512, 256, 0, stream>>>(W_attn, Wa, NI * 1024);
  cast_f32_bf16<<<512, 256, 0, stream>>>(W_hh, Whh, NG * 512);
  cast_f32_bf16<<<512, 256, 0, stream>>>(W_comb, Wc, NH * 1024);
  cast_f32_bf16<<<512, 256, 0, stream>>>(W_ih, Wih, NG * 512);
  cast_f32_bf16<<<512, 256, 0, stream>>>(W_out, Wout, 512 * 512);
  zt_fp8<<<4096, 256, 0, stream>>>(XZ, Zsc, Wc);
  init_kernel<<<512, 256, 0, stream>>>(x, Xt, Hbf, bar);
  lxgx0_kernel<<<256, 256, 0, stream>>>(Xt, Wa, Wc, b_comb, Lx, Gx);

  KParams prm;
  prm.Z8 = (const unsigned char*)XZ; prm.Zsc = Zsc;
  prm.Wa = Wa; prm.Whh = Whh; prm.Wc = Wc; prm.Wih = Wih; prm.Wout = Wout;
  prm.Xt = Xt; prm.Hbf = Hbf; prm.Gbf = Gbf;
  prm.logits = logits; prm.gh = gh; prm.Lx = Lx; prm.Gx = Gx; prm.Gp = Gp;
  prm.x = x; prm.b_attn = b_attn; prm.b_hh = b_hh; prm.b_ih = b_ih; prm.b_out = b_out;
  prm.b_comb = b_comb;
  prm.out = (float*)d_out;
  prm.bar = bar;

  void* kargs[] = { &prm };
  hipError_t e = hipLaunchCooperativeKernel((const void*)persistent_kernel,
                                            dim3(NBLK), dim3(256), kargs, 0, stream);
  if (e != hipSuccess) {
    persistent_kernel<<<dim3(NBLK), dim3(256), 0, stream>>>(prm);
  }
}